// Round 1
// baseline (725.379 us; speedup 1.0000x reference)
//
#include <hip/hip_runtime.h>

#define D 128
#define N_GRAPHS 64
#define PCHUNK 128

// ---------------- CSR build ----------------

__global__ void count_kernel(const int* __restrict__ dst, int* __restrict__ cnt, int E) {
    int e = blockIdx.x * blockDim.x + threadIdx.x;
    if (e < E) atomicAdd(&cnt[dst[e]], 1);
}

__global__ void dinv_kernel(const int* __restrict__ cnt, float* __restrict__ dinv, int n) {
    int i = blockIdx.x * blockDim.x + threadIdx.x;
    // deg = in-degree + 1 (self loop) >= 1 always
    if (i < n) dinv[i] = rsqrtf((float)(cnt[i] + 1));
}

// single-block exclusive scan of cnt[0..n) -> rowptr[0..n]
__global__ void scan_kernel(const int* __restrict__ cnt, int* __restrict__ rowptr, int n) {
    __shared__ int sm[256];
    __shared__ int sbase;
    int t = threadIdx.x;
    if (t == 0) sbase = 0;
    __syncthreads();
    for (int start = 0; start < n; start += 256) {
        int i = start + t;
        int v = (i < n) ? cnt[i] : 0;
        sm[t] = v;
        __syncthreads();
        // Hillis-Steele inclusive scan
        for (int off = 1; off < 256; off <<= 1) {
            int add = (t >= off) ? sm[t - off] : 0;
            __syncthreads();
            sm[t] += add;
            __syncthreads();
        }
        int incl = sm[t];
        int base = sbase;
        if (i < n) rowptr[i] = base + incl - v;  // exclusive
        __syncthreads();                          // all reads of sbase done
        if (t == 255) sbase = base + incl;        // incl at t=255 == chunk total
        __syncthreads();
    }
    if (t == 0) rowptr[n] = sbase;
}

__global__ void fill_kernel(const int* __restrict__ src, const int* __restrict__ dst,
                            const int* __restrict__ rowptr, int* __restrict__ fill,
                            int* __restrict__ col, float* __restrict__ wgt,
                            const float* __restrict__ dinv, int E) {
    int e = blockIdx.x * blockDim.x + threadIdx.x;
    if (e < E) {
        int s = src[e], d = dst[e];
        int pos = rowptr[d] + atomicAdd(&fill[d], 1);
        col[pos] = s;
        wgt[pos] = dinv[s] * dinv[d];
    }
}

// ---------------- dense GEMM: C[M x 128] = A[M x 128] @ W[128 x 128] ----------------
// block 256 threads = 16x16; tile 64 rows x 128 cols; 4x8 acc per thread

__global__ __launch_bounds__(256) void gemm_kernel(const float* __restrict__ A,
                                                   const float* __restrict__ W,
                                                   float* __restrict__ C, int M) {
    __shared__ float As[8][64];
    __shared__ float Ws[8][128];
    int tid = threadIdx.x;
    int tx = tid & 15;   // col group: cols 8*tx .. 8*tx+7
    int ty = tid >> 4;   // row group: rows 4*ty .. 4*ty+3
    int row0 = blockIdx.x * 64;
    float acc[4][8];
#pragma unroll
    for (int m = 0; m < 4; ++m)
#pragma unroll
        for (int c = 0; c < 8; ++c) acc[m][c] = 0.f;

    for (int kk = 0; kk < D; kk += 8) {
        if (tid < 128) {
            int r = tid >> 1;
            int kq = tid & 1;
            float4 v = make_float4(0.f, 0.f, 0.f, 0.f);
            if (row0 + r < M)
                v = *(const float4*)&A[(size_t)(row0 + r) * D + kk + kq * 4];
            As[kq * 4 + 0][r] = v.x;
            As[kq * 4 + 1][r] = v.y;
            As[kq * 4 + 2][r] = v.z;
            As[kq * 4 + 3][r] = v.w;
        } else {
            int t2 = tid - 128;
#pragma unroll
            for (int j = 0; j < 2; ++j) {
                int idx = t2 + j * 128;
                int k = idx >> 5;
                int c4 = idx & 31;
                float4 v = *(const float4*)&W[(size_t)(kk + k) * D + c4 * 4];
                *(float4*)&Ws[k][c4 * 4] = v;
            }
        }
        __syncthreads();
#pragma unroll
        for (int k = 0; k < 8; ++k) {
            float4 a  = *(const float4*)&As[k][ty * 4];
            float4 w0 = *(const float4*)&Ws[k][tx * 8];
            float4 w1 = *(const float4*)&Ws[k][tx * 8 + 4];
            float am[4] = {a.x, a.y, a.z, a.w};
            float wv[8] = {w0.x, w0.y, w0.z, w0.w, w1.x, w1.y, w1.z, w1.w};
#pragma unroll
            for (int m = 0; m < 4; ++m)
#pragma unroll
                for (int c = 0; c < 8; ++c) acc[m][c] += am[m] * wv[c];
        }
        __syncthreads();
    }
#pragma unroll
    for (int m = 0; m < 4; ++m) {
        int row = row0 + ty * 4 + m;
        if (row < M) {
            *(float4*)&C[(size_t)row * D + tx * 8] =
                make_float4(acc[m][0], acc[m][1], acc[m][2], acc[m][3]);
            *(float4*)&C[(size_t)row * D + tx * 8 + 4] =
                make_float4(acc[m][4], acc[m][5], acc[m][6], acc[m][7]);
        }
    }
}

// ---------------- aggregation (gather over CSR) + bias (+ReLU) ----------------
// one block per node, thread per feature

__global__ __launch_bounds__(128) void agg_kernel(const float* __restrict__ h,
                                                  const int* __restrict__ rowptr,
                                                  const int* __restrict__ col,
                                                  const float* __restrict__ wgt,
                                                  const float* __restrict__ dinv,
                                                  const float* __restrict__ bias,
                                                  float* __restrict__ out, int relu) {
    int node = blockIdx.x;
    int f = threadIdx.x;
    float di = dinv[node];
    float acc = di * di * h[(size_t)node * D + f];  // self loop
    int beg = rowptr[node], end = rowptr[node + 1];
    for (int k = beg; k < end; ++k) {
        int s = col[k];
        float w = wgt[k];
        acc += w * h[(size_t)s * D + f];
    }
    acc += bias[f];
    if (relu) acc = fmaxf(acc, 0.f);
    out[(size_t)node * D + f] = acc;
}

// ---------------- pooling ----------------

__global__ void countg_kernel(const int* __restrict__ batch, int* __restrict__ cntg, int n) {
    int i = blockIdx.x * blockDim.x + threadIdx.x;
    if (i < n) atomicAdd(&cntg[batch[i]], 1);
}

// batch is sorted: chunked partial sums, few atomics
__global__ __launch_bounds__(128) void pool_kernel(const float* __restrict__ h,
                                                   const int* __restrict__ batch,
                                                   float* __restrict__ out, int n) {
    int f = threadIdx.x;
    int start = blockIdx.x * PCHUNK;
    if (start >= n) return;
    int end = min(start + PCHUNK, n);
    int cur = batch[start];
    float acc = 0.f;
    for (int i = start; i < end; ++i) {
        int g = batch[i];  // wave-uniform broadcast load
        if (g != cur) {
            atomicAdd(&out[cur * D + f], acc);
            acc = 0.f;
            cur = g;
        }
        acc += h[(size_t)i * D + f];
    }
    atomicAdd(&out[cur * D + f], acc);
}

__global__ void div_kernel(float* __restrict__ out, const int* __restrict__ cntg, int total) {
    int i = blockIdx.x * blockDim.x + threadIdx.x;
    if (i < total) {
        int g = i >> 7;  // D==128
        float c = (float)max(cntg[g], 1);
        out[i] /= c;
    }
}

// ---------------- launcher ----------------

extern "C" void kernel_launch(void* const* d_in, const int* in_sizes, int n_in,
                              void* d_out, int out_size, void* d_ws, size_t ws_size,
                              hipStream_t stream) {
    const float* x  = (const float*)d_in[0];
    const int*   ei = (const int*)d_in[1];
    const int*   batch = (const int*)d_in[2];
    const float* W1 = (const float*)d_in[3];
    const float* b1 = (const float*)d_in[4];
    const float* W2 = (const float*)d_in[5];
    const float* b2 = (const float*)d_in[6];
    float* out = (float*)d_out;

    const int n = in_sizes[2];       // 40000 nodes
    const int E = in_sizes[1] / 2;   // 640000 edges
    const int* src = ei;             // edge_index[0] = message sources
    const int* dst = ei + E;         // edge_index[1] = aggregation targets

    // workspace carve-up (256B aligned)
    char* ws = (char*)d_ws;
    size_t off = 0;
    auto carve = [&](size_t bytes) {
        size_t o = off;
        off = (off + bytes + 255) & ~(size_t)255;
        return (void*)(ws + o);
    };
    int*   cnt    = (int*)carve((size_t)n * 4);
    int*   rowptr = (int*)carve((size_t)(n + 1) * 4);
    int*   fill   = (int*)carve((size_t)n * 4);
    float* dinv   = (float*)carve((size_t)n * 4);
    int*   col    = (int*)carve((size_t)E * 4);
    float* wgt    = (float*)carve((size_t)E * 4);
    float* bufA   = (float*)carve((size_t)n * D * 4);
    float* bufB   = (float*)carve((size_t)n * D * 4);
    int*   cntg   = (int*)carve((size_t)N_GRAPHS * 4);
    (void)ws_size;

    // zero-init (ws/out are poisoned 0xAA before every call)
    hipMemsetAsync(cnt,  0, (size_t)n * 4, stream);
    hipMemsetAsync(fill, 0, (size_t)n * 4, stream);
    hipMemsetAsync(cntg, 0, (size_t)N_GRAPHS * 4, stream);
    hipMemsetAsync(out,  0, (size_t)out_size * 4, stream);

    // CSR build (shared by both layers)
    count_kernel<<<(E + 255) / 256, 256, 0, stream>>>(dst, cnt, E);
    dinv_kernel<<<(n + 255) / 256, 256, 0, stream>>>(cnt, dinv, n);
    scan_kernel<<<1, 256, 0, stream>>>(cnt, rowptr, n);
    fill_kernel<<<(E + 255) / 256, 256, 0, stream>>>(src, dst, rowptr, fill, col, wgt, dinv, E);

    // layer 1: h1 = x @ W1 ; agg + b1 + ReLU
    gemm_kernel<<<(n + 63) / 64, 256, 0, stream>>>(x, W1, bufA, n);
    agg_kernel<<<n, 128, 0, stream>>>(bufA, rowptr, col, wgt, dinv, b1, bufB, 1);

    // layer 2: h2 = h1' @ W2 ; agg + b2 (no ReLU)
    gemm_kernel<<<(n + 63) / 64, 256, 0, stream>>>(bufB, W2, bufA, n);
    agg_kernel<<<n, 128, 0, stream>>>(bufA, rowptr, col, wgt, dinv, b2, bufB, 0);

    // global mean pool
    countg_kernel<<<(n + 255) / 256, 256, 0, stream>>>(batch, cntg, n);
    pool_kernel<<<(n + PCHUNK - 1) / PCHUNK, 128, 0, stream>>>(bufB, batch, out, n);
    div_kernel<<<(out_size + 255) / 256, 256, 0, stream>>>(out, cntg, out_size);
}

// Round 2
// 421.182 us; speedup vs baseline: 1.7222x; 1.7222x over previous
//
#include <hip/hip_runtime.h>

#define D 128
#define N_GRAPHS 64
#define PCHUNK 128

// ---------------- CSR build ----------------

__global__ void count_kernel(const int* __restrict__ dst, int* __restrict__ cnt, int E) {
    int e = blockIdx.x * blockDim.x + threadIdx.x;
    if (e < E) atomicAdd(&cnt[dst[e]], 1);
}

__global__ void dinv_kernel(const int* __restrict__ cnt, float* __restrict__ dinv, int n) {
    int i = blockIdx.x * blockDim.x + threadIdx.x;
    // deg = in-degree + 1 (self loop) >= 1 always
    if (i < n) dinv[i] = rsqrtf((float)(cnt[i] + 1));
}

// single-block exclusive scan of cnt[0..n) -> rowptr[0..n]
// 1024 threads, wave-shuffle scans: ~3 barriers per 1024-elem chunk
__global__ __launch_bounds__(1024) void scan_kernel(const int* __restrict__ cnt,
                                                    int* __restrict__ rowptr, int n) {
    __shared__ int swave[16];
    __shared__ int sbase;
    int t = threadIdx.x;
    int lane = t & 63, wave = t >> 6;
    if (t == 0) sbase = 0;
    __syncthreads();
    for (int start = 0; start < n; start += 1024) {
        int i = start + t;
        int orig = (i < n) ? cnt[i] : 0;
        int v = orig;
        // inclusive scan within wave (64 lanes)
#pragma unroll
        for (int off = 1; off < 64; off <<= 1) {
            int u = __shfl_up(v, off, 64);
            if (lane >= off) v += u;
        }
        if (lane == 63) swave[wave] = v;
        __syncthreads();
        if (wave == 0) {
            int wv = (lane < 16) ? swave[lane] : 0;
#pragma unroll
            for (int off = 1; off < 16; off <<= 1) {
                int u = __shfl_up(wv, off, 64);
                if (lane >= off) wv += u;
            }
            if (lane < 16) swave[lane] = wv;  // inclusive per-wave totals
        }
        __syncthreads();
        int wprefix = (wave > 0) ? swave[wave - 1] : 0;
        int base = sbase;
        int incl = v + wprefix;
        if (i < n) rowptr[i] = base + incl - orig;  // exclusive
        __syncthreads();                             // all reads of sbase/swave done
        if (t == 1023) sbase = base + incl;          // incl at last thread == chunk total
        __syncthreads();
    }
    if (t == 0) rowptr[n] = sbase;
}

__global__ void fill_kernel(const int* __restrict__ src, const int* __restrict__ dst,
                            const int* __restrict__ rowptr, int* __restrict__ fill,
                            int* __restrict__ col, float* __restrict__ wgt,
                            const float* __restrict__ dinv, int E) {
    int e = blockIdx.x * blockDim.x + threadIdx.x;
    if (e < E) {
        int s = src[e], d = dst[e];
        int pos = rowptr[d] + atomicAdd(&fill[d], 1);
        col[pos] = s;
        wgt[pos] = dinv[s] * dinv[d];
    }
}

// ---------------- dense GEMM: C[M x 128] = A[M x 128] @ W[128 x 128] ----------------
// block 256 threads = 16x16; tile 64 rows x 128 cols; 4x8 acc per thread

__global__ __launch_bounds__(256) void gemm_kernel(const float* __restrict__ A,
                                                   const float* __restrict__ W,
                                                   float* __restrict__ C, int M) {
    __shared__ float As[8][64];
    __shared__ float Ws[8][128];
    int tid = threadIdx.x;
    int tx = tid & 15;   // col group: cols 8*tx .. 8*tx+7
    int ty = tid >> 4;   // row group: rows 4*ty .. 4*ty+3
    int row0 = blockIdx.x * 64;
    float acc[4][8];
#pragma unroll
    for (int m = 0; m < 4; ++m)
#pragma unroll
        for (int c = 0; c < 8; ++c) acc[m][c] = 0.f;

    for (int kk = 0; kk < D; kk += 8) {
        if (tid < 128) {
            int r = tid >> 1;
            int kq = tid & 1;
            float4 v = make_float4(0.f, 0.f, 0.f, 0.f);
            if (row0 + r < M)
                v = *(const float4*)&A[(size_t)(row0 + r) * D + kk + kq * 4];
            As[kq * 4 + 0][r] = v.x;
            As[kq * 4 + 1][r] = v.y;
            As[kq * 4 + 2][r] = v.z;
            As[kq * 4 + 3][r] = v.w;
        } else {
            int t2 = tid - 128;
#pragma unroll
            for (int j = 0; j < 2; ++j) {
                int idx = t2 + j * 128;
                int k = idx >> 5;
                int c4 = idx & 31;
                float4 v = *(const float4*)&W[(size_t)(kk + k) * D + c4 * 4];
                *(float4*)&Ws[k][c4 * 4] = v;
            }
        }
        __syncthreads();
#pragma unroll
        for (int k = 0; k < 8; ++k) {
            float4 a  = *(const float4*)&As[k][ty * 4];
            float4 w0 = *(const float4*)&Ws[k][tx * 8];
            float4 w1 = *(const float4*)&Ws[k][tx * 8 + 4];
            float am[4] = {a.x, a.y, a.z, a.w};
            float wv[8] = {w0.x, w0.y, w0.z, w0.w, w1.x, w1.y, w1.z, w1.w};
#pragma unroll
            for (int m = 0; m < 4; ++m)
#pragma unroll
                for (int c = 0; c < 8; ++c) acc[m][c] += am[m] * wv[c];
        }
        __syncthreads();
    }
#pragma unroll
    for (int m = 0; m < 4; ++m) {
        int row = row0 + ty * 4 + m;
        if (row < M) {
            *(float4*)&C[(size_t)row * D + tx * 8] =
                make_float4(acc[m][0], acc[m][1], acc[m][2], acc[m][3]);
            *(float4*)&C[(size_t)row * D + tx * 8 + 4] =
                make_float4(acc[m][4], acc[m][5], acc[m][6], acc[m][7]);
        }
    }
}

// ---------------- aggregation (gather over CSR) + bias (+ReLU) ----------------
// one block per node, thread per feature

__global__ __launch_bounds__(128) void agg_kernel(const float* __restrict__ h,
                                                  const int* __restrict__ rowptr,
                                                  const int* __restrict__ col,
                                                  const float* __restrict__ wgt,
                                                  const float* __restrict__ dinv,
                                                  const float* __restrict__ bias,
                                                  float* __restrict__ out, int relu) {
    int node = blockIdx.x;
    int f = threadIdx.x;
    float di = dinv[node];
    float acc = di * di * h[(size_t)node * D + f];  // self loop
    int beg = rowptr[node], end = rowptr[node + 1];
    for (int k = beg; k < end; ++k) {
        int s = col[k];
        float w = wgt[k];
        acc += w * h[(size_t)s * D + f];
    }
    acc += bias[f];
    if (relu) acc = fmaxf(acc, 0.f);
    out[(size_t)node * D + f] = acc;
}

// ---------------- pooling ----------------

// batch is sorted: per-graph counts via binary search (NO atomics — 40000
// atomics onto 64 addresses was 188 us of XCD line ping-pong)
__global__ void graph_count_kernel(const int* __restrict__ batch, int* __restrict__ cntg, int n) {
    int g = threadIdx.x;
    if (g >= N_GRAPHS) return;
    int lo = 0, hi = n;
    while (lo < hi) { int mid = (lo + hi) >> 1; if (batch[mid] < g) lo = mid + 1; else hi = mid; }
    int lb0 = lo;
    int g1 = g + 1;
    lo = 0; hi = n;
    while (lo < hi) { int mid = (lo + hi) >> 1; if (batch[mid] < g1) lo = mid + 1; else hi = mid; }
    cntg[g] = lo - lb0;
}

// batch is sorted: chunked partial sums, few atomics
__global__ __launch_bounds__(128) void pool_kernel(const float* __restrict__ h,
                                                   const int* __restrict__ batch,
                                                   float* __restrict__ out, int n) {
    int f = threadIdx.x;
    int start = blockIdx.x * PCHUNK;
    if (start >= n) return;
    int end = min(start + PCHUNK, n);
    int cur = batch[start];
    float acc = 0.f;
    for (int i = start; i < end; ++i) {
        int g = batch[i];  // wave-uniform broadcast load
        if (g != cur) {
            atomicAdd(&out[cur * D + f], acc);
            acc = 0.f;
            cur = g;
        }
        acc += h[(size_t)i * D + f];
    }
    atomicAdd(&out[cur * D + f], acc);
}

__global__ void div_kernel(float* __restrict__ out, const int* __restrict__ cntg, int total) {
    int i = blockIdx.x * blockDim.x + threadIdx.x;
    if (i < total) {
        int g = i >> 7;  // D==128
        float c = (float)max(cntg[g], 1);
        out[i] /= c;
    }
}

// ---------------- launcher ----------------

extern "C" void kernel_launch(void* const* d_in, const int* in_sizes, int n_in,
                              void* d_out, int out_size, void* d_ws, size_t ws_size,
                              hipStream_t stream) {
    const float* x  = (const float*)d_in[0];
    const int*   ei = (const int*)d_in[1];
    const int*   batch = (const int*)d_in[2];
    const float* W1 = (const float*)d_in[3];
    const float* b1 = (const float*)d_in[4];
    const float* W2 = (const float*)d_in[5];
    const float* b2 = (const float*)d_in[6];
    float* out = (float*)d_out;

    const int n = in_sizes[2];       // 40000 nodes
    const int E = in_sizes[1] / 2;   // 640000 edges
    const int* src = ei;             // edge_index[0] = message sources
    const int* dst = ei + E;         // edge_index[1] = aggregation targets

    // workspace carve-up (256B aligned)
    char* ws = (char*)d_ws;
    size_t off = 0;
    auto carve = [&](size_t bytes) {
        size_t o = off;
        off = (off + bytes + 255) & ~(size_t)255;
        return (void*)(ws + o);
    };
    int*   cnt    = (int*)carve((size_t)n * 4);
    int*   rowptr = (int*)carve((size_t)(n + 1) * 4);
    int*   fill   = (int*)carve((size_t)n * 4);
    float* dinv   = (float*)carve((size_t)n * 4);
    int*   col    = (int*)carve((size_t)E * 4);
    float* wgt    = (float*)carve((size_t)E * 4);
    float* bufA   = (float*)carve((size_t)n * D * 4);
    float* bufB   = (float*)carve((size_t)n * D * 4);
    int*   cntg   = (int*)carve((size_t)N_GRAPHS * 4);
    (void)ws_size;

    // zero-init (ws/out are poisoned 0xAA before every call)
    hipMemsetAsync(cnt,  0, (size_t)n * 4, stream);
    hipMemsetAsync(fill, 0, (size_t)n * 4, stream);
    hipMemsetAsync(out,  0, (size_t)out_size * 4, stream);

    // CSR build (shared by both layers)
    count_kernel<<<(E + 255) / 256, 256, 0, stream>>>(dst, cnt, E);
    dinv_kernel<<<(n + 255) / 256, 256, 0, stream>>>(cnt, dinv, n);
    scan_kernel<<<1, 1024, 0, stream>>>(cnt, rowptr, n);
    fill_kernel<<<(E + 255) / 256, 256, 0, stream>>>(src, dst, rowptr, fill, col, wgt, dinv, E);

    // layer 1: h1 = x @ W1 ; agg + b1 + ReLU
    gemm_kernel<<<(n + 63) / 64, 256, 0, stream>>>(x, W1, bufA, n);
    agg_kernel<<<n, 128, 0, stream>>>(bufA, rowptr, col, wgt, dinv, b1, bufB, 1);

    // layer 2: h2 = h1' @ W2 ; agg + b2 (no ReLU)
    gemm_kernel<<<(n + 63) / 64, 256, 0, stream>>>(bufB, W2, bufA, n);
    agg_kernel<<<n, 128, 0, stream>>>(bufA, rowptr, col, wgt, dinv, b2, bufB, 0);

    // global mean pool
    graph_count_kernel<<<1, 64, 0, stream>>>(batch, cntg, n);
    pool_kernel<<<(n + PCHUNK - 1) / PCHUNK, 128, 0, stream>>>(bufB, batch, out, n);
    div_kernel<<<(out_size + 255) / 256, 256, 0, stream>>>(out, cntg, out_size);
}

// Round 3
// 351.332 us; speedup vs baseline: 2.0647x; 1.1988x over previous
//
#include <hip/hip_runtime.h>

#define D 128
#define N_GRAPHS 64
#define PCHUNK 64

// ---------------- CSR build ----------------

__global__ void count_kernel(const int* __restrict__ dst, int* __restrict__ cnt, int E) {
    int e = blockIdx.x * blockDim.x + threadIdx.x;
    if (e < E) atomicAdd(&cnt[dst[e]], 1);
}

__global__ void dinv_kernel(const int* __restrict__ cnt, float* __restrict__ dinv, int n) {
    int i = blockIdx.x * blockDim.x + threadIdx.x;
    // deg = in-degree + 1 (self loop) >= 1 always
    if (i < n) dinv[i] = rsqrtf((float)(cnt[i] + 1));
}

// single-block exclusive scan of cnt[0..n) -> rowptr[0..n]
// 1024 threads, wave-shuffle scans: ~3 barriers per 1024-elem chunk
__global__ __launch_bounds__(1024) void scan_kernel(const int* __restrict__ cnt,
                                                    int* __restrict__ rowptr, int n) {
    __shared__ int swave[16];
    __shared__ int sbase;
    int t = threadIdx.x;
    int lane = t & 63, wave = t >> 6;
    if (t == 0) sbase = 0;
    __syncthreads();
    for (int start = 0; start < n; start += 1024) {
        int i = start + t;
        int orig = (i < n) ? cnt[i] : 0;
        int v = orig;
        // inclusive scan within wave (64 lanes)
#pragma unroll
        for (int off = 1; off < 64; off <<= 1) {
            int u = __shfl_up(v, off, 64);
            if (lane >= off) v += u;
        }
        if (lane == 63) swave[wave] = v;
        __syncthreads();
        if (wave == 0) {
            int wv = (lane < 16) ? swave[lane] : 0;
#pragma unroll
            for (int off = 1; off < 16; off <<= 1) {
                int u = __shfl_up(wv, off, 64);
                if (lane >= off) wv += u;
            }
            if (lane < 16) swave[lane] = wv;  // inclusive per-wave totals
        }
        __syncthreads();
        int wprefix = (wave > 0) ? swave[wave - 1] : 0;
        int base = sbase;
        int incl = v + wprefix;
        if (i < n) rowptr[i] = base + incl - orig;  // exclusive
        __syncthreads();                             // all reads of sbase/swave done
        if (t == 1023) sbase = base + incl;          // incl at last thread == chunk total
        __syncthreads();
    }
    if (t == 0) rowptr[n] = sbase;
}

__global__ void fill_kernel(const int* __restrict__ src, const int* __restrict__ dst,
                            const int* __restrict__ rowptr, int* __restrict__ fill,
                            int* __restrict__ col, float* __restrict__ wgt,
                            const float* __restrict__ dinv, int E) {
    int e = blockIdx.x * blockDim.x + threadIdx.x;
    if (e < E) {
        int s = src[e], d = dst[e];
        int pos = rowptr[d] + atomicAdd(&fill[d], 1);
        col[pos] = s;
        wgt[pos] = dinv[s] * dinv[d];
    }
}

// ---------------- dense GEMM: C[M x 128] = A[M x 128] @ W[128 x 128] ----------------
// block 256 threads = 16x16; tile 64 rows x 128 cols; 4x8 acc per thread

__global__ __launch_bounds__(256) void gemm_kernel(const float* __restrict__ A,
                                                   const float* __restrict__ W,
                                                   float* __restrict__ C, int M) {
    __shared__ float As[8][64];
    __shared__ float Ws[8][128];
    int tid = threadIdx.x;
    int tx = tid & 15;   // col group: cols 8*tx .. 8*tx+7
    int ty = tid >> 4;   // row group: rows 4*ty .. 4*ty+3
    int row0 = blockIdx.x * 64;
    float acc[4][8];
#pragma unroll
    for (int m = 0; m < 4; ++m)
#pragma unroll
        for (int c = 0; c < 8; ++c) acc[m][c] = 0.f;

    for (int kk = 0; kk < D; kk += 8) {
        if (tid < 128) {
            int r = tid >> 1;
            int kq = tid & 1;
            float4 v = make_float4(0.f, 0.f, 0.f, 0.f);
            if (row0 + r < M)
                v = *(const float4*)&A[(size_t)(row0 + r) * D + kk + kq * 4];
            As[kq * 4 + 0][r] = v.x;
            As[kq * 4 + 1][r] = v.y;
            As[kq * 4 + 2][r] = v.z;
            As[kq * 4 + 3][r] = v.w;
        } else {
            int t2 = tid - 128;
#pragma unroll
            for (int j = 0; j < 2; ++j) {
                int idx = t2 + j * 128;
                int k = idx >> 5;
                int c4 = idx & 31;
                float4 v = *(const float4*)&W[(size_t)(kk + k) * D + c4 * 4];
                *(float4*)&Ws[k][c4 * 4] = v;
            }
        }
        __syncthreads();
#pragma unroll
        for (int k = 0; k < 8; ++k) {
            float4 a  = *(const float4*)&As[k][ty * 4];
            float4 w0 = *(const float4*)&Ws[k][tx * 8];
            float4 w1 = *(const float4*)&Ws[k][tx * 8 + 4];
            float am[4] = {a.x, a.y, a.z, a.w};
            float wv[8] = {w0.x, w0.y, w0.z, w0.w, w1.x, w1.y, w1.z, w1.w};
#pragma unroll
            for (int m = 0; m < 4; ++m)
#pragma unroll
                for (int c = 0; c < 8; ++c) acc[m][c] += am[m] * wv[c];
        }
        __syncthreads();
    }
#pragma unroll
    for (int m = 0; m < 4; ++m) {
        int row = row0 + ty * 4 + m;
        if (row < M) {
            *(float4*)&C[(size_t)row * D + tx * 8] =
                make_float4(acc[m][0], acc[m][1], acc[m][2], acc[m][3]);
            *(float4*)&C[(size_t)row * D + tx * 8 + 4] =
                make_float4(acc[m][4], acc[m][5], acc[m][6], acc[m][7]);
        }
    }
}

// ---------------- aggregation (gather over CSR) + bias (+ReLU) ----------------
// 2 nodes per wave (half-wave of 32 lanes x float4 = full 512B row per load),
// edge loop unrolled x4 -> 4 independent 512B gathers in flight per half-wave.

__global__ __launch_bounds__(256) void agg_kernel(const float* __restrict__ h,
                                                  const int* __restrict__ rowptr,
                                                  const int* __restrict__ col,
                                                  const float* __restrict__ wgt,
                                                  const float* __restrict__ dinv,
                                                  const float* __restrict__ bias,
                                                  float* __restrict__ out, int relu, int n) {
    int tid = threadIdx.x;
    int lane32 = tid & 31;
    int pair = tid >> 5;  // 0..7: node slot within block
    int node = blockIdx.x * 8 + pair;
    if (node >= n) return;
    const float4* __restrict__ h4 = (const float4*)h;

    float di = dinv[node];
    float ws = di * di;
    float4 self = h4[(size_t)node * 32 + lane32];
    float4 acc;
    acc.x = ws * self.x; acc.y = ws * self.y; acc.z = ws * self.z; acc.w = ws * self.w;

    int beg = rowptr[node], end = rowptr[node + 1];
    int k = beg;
    for (; k + 4 <= end; k += 4) {
        int s0 = col[k],     s1 = col[k + 1], s2 = col[k + 2], s3 = col[k + 3];
        float w0 = wgt[k],   w1 = wgt[k + 1], w2 = wgt[k + 2], w3 = wgt[k + 3];
        float4 v0 = h4[(size_t)s0 * 32 + lane32];
        float4 v1 = h4[(size_t)s1 * 32 + lane32];
        float4 v2 = h4[(size_t)s2 * 32 + lane32];
        float4 v3 = h4[(size_t)s3 * 32 + lane32];
        acc.x = fmaf(w0, v0.x, acc.x); acc.y = fmaf(w0, v0.y, acc.y);
        acc.z = fmaf(w0, v0.z, acc.z); acc.w = fmaf(w0, v0.w, acc.w);
        acc.x = fmaf(w1, v1.x, acc.x); acc.y = fmaf(w1, v1.y, acc.y);
        acc.z = fmaf(w1, v1.z, acc.z); acc.w = fmaf(w1, v1.w, acc.w);
        acc.x = fmaf(w2, v2.x, acc.x); acc.y = fmaf(w2, v2.y, acc.y);
        acc.z = fmaf(w2, v2.z, acc.z); acc.w = fmaf(w2, v2.w, acc.w);
        acc.x = fmaf(w3, v3.x, acc.x); acc.y = fmaf(w3, v3.y, acc.y);
        acc.z = fmaf(w3, v3.z, acc.z); acc.w = fmaf(w3, v3.w, acc.w);
    }
    for (; k < end; ++k) {
        int s = col[k];
        float w = wgt[k];
        float4 v = h4[(size_t)s * 32 + lane32];
        acc.x = fmaf(w, v.x, acc.x); acc.y = fmaf(w, v.y, acc.y);
        acc.z = fmaf(w, v.z, acc.z); acc.w = fmaf(w, v.w, acc.w);
    }

    float4 b4 = ((const float4*)bias)[lane32];
    acc.x += b4.x; acc.y += b4.y; acc.z += b4.z; acc.w += b4.w;
    if (relu) {
        acc.x = fmaxf(acc.x, 0.f); acc.y = fmaxf(acc.y, 0.f);
        acc.z = fmaxf(acc.z, 0.f); acc.w = fmaxf(acc.w, 0.f);
    }
    ((float4*)out)[(size_t)node * 32 + lane32] = acc;
}

// ---------------- pooling ----------------

// batch is sorted: per-graph counts via binary search (NO atomics — 40000
// atomics onto 64 addresses was 188 us of XCD line ping-pong)
__global__ void graph_count_kernel(const int* __restrict__ batch, int* __restrict__ cntg, int n) {
    int g = threadIdx.x;
    if (g >= N_GRAPHS) return;
    int lo = 0, hi = n;
    while (lo < hi) { int mid = (lo + hi) >> 1; if (batch[mid] < g) lo = mid + 1; else hi = mid; }
    int lb0 = lo;
    int g1 = g + 1;
    lo = 0; hi = n;
    while (lo < hi) { int mid = (lo + hi) >> 1; if (batch[mid] < g1) lo = mid + 1; else hi = mid; }
    cntg[g] = lo - lb0;
}

// batch is sorted: chunked partial sums, few atomics
__global__ __launch_bounds__(128) void pool_kernel(const float* __restrict__ h,
                                                   const int* __restrict__ batch,
                                                   float* __restrict__ out, int n) {
    int f = threadIdx.x;
    int start = blockIdx.x * PCHUNK;
    if (start >= n) return;
    int end = min(start + PCHUNK, n);
    int cur = batch[start];
    float acc = 0.f;
    for (int i = start; i < end; ++i) {
        int g = batch[i];  // wave-uniform broadcast load
        if (g != cur) {
            atomicAdd(&out[cur * D + f], acc);
            acc = 0.f;
            cur = g;
        }
        acc += h[(size_t)i * D + f];
    }
    atomicAdd(&out[cur * D + f], acc);
}

__global__ void div_kernel(float* __restrict__ out, const int* __restrict__ cntg, int total) {
    int i = blockIdx.x * blockDim.x + threadIdx.x;
    if (i < total) {
        int g = i >> 7;  // D==128
        float c = (float)max(cntg[g], 1);
        out[i] /= c;
    }
}

// ---------------- launcher ----------------

extern "C" void kernel_launch(void* const* d_in, const int* in_sizes, int n_in,
                              void* d_out, int out_size, void* d_ws, size_t ws_size,
                              hipStream_t stream) {
    const float* x  = (const float*)d_in[0];
    const int*   ei = (const int*)d_in[1];
    const int*   batch = (const int*)d_in[2];
    const float* W1 = (const float*)d_in[3];
    const float* b1 = (const float*)d_in[4];
    const float* W2 = (const float*)d_in[5];
    const float* b2 = (const float*)d_in[6];
    float* out = (float*)d_out;

    const int n = in_sizes[2];       // 40000 nodes
    const int E = in_sizes[1] / 2;   // 640000 edges
    const int* src = ei;             // edge_index[0] = message sources
    const int* dst = ei + E;         // edge_index[1] = aggregation targets

    // workspace carve-up (256B aligned)
    char* ws = (char*)d_ws;
    size_t off = 0;
    auto carve = [&](size_t bytes) {
        size_t o = off;
        off = (off + bytes + 255) & ~(size_t)255;
        return (void*)(ws + o);
    };
    int*   cnt    = (int*)carve((size_t)n * 4);
    int*   rowptr = (int*)carve((size_t)(n + 1) * 4);
    int*   fill   = (int*)carve((size_t)n * 4);
    float* dinv   = (float*)carve((size_t)n * 4);
    int*   col    = (int*)carve((size_t)E * 4);
    float* wgt    = (float*)carve((size_t)E * 4);
    float* bufA   = (float*)carve((size_t)n * D * 4);
    float* bufB   = (float*)carve((size_t)n * D * 4);
    int*   cntg   = (int*)carve((size_t)N_GRAPHS * 4);
    (void)ws_size;

    // zero-init (ws/out are poisoned 0xAA before every call)
    hipMemsetAsync(cnt,  0, (size_t)n * 4, stream);
    hipMemsetAsync(fill, 0, (size_t)n * 4, stream);
    hipMemsetAsync(out,  0, (size_t)out_size * 4, stream);

    // CSR build (shared by both layers)
    count_kernel<<<(E + 255) / 256, 256, 0, stream>>>(dst, cnt, E);
    dinv_kernel<<<(n + 255) / 256, 256, 0, stream>>>(cnt, dinv, n);
    scan_kernel<<<1, 1024, 0, stream>>>(cnt, rowptr, n);
    fill_kernel<<<(E + 255) / 256, 256, 0, stream>>>(src, dst, rowptr, fill, col, wgt, dinv, E);

    // layer 1: h1 = x @ W1 ; agg + b1 + ReLU
    gemm_kernel<<<(n + 63) / 64, 256, 0, stream>>>(x, W1, bufA, n);
    agg_kernel<<<(n + 7) / 8, 256, 0, stream>>>(bufA, rowptr, col, wgt, dinv, b1, bufB, 1, n);

    // layer 2: h2 = h1' @ W2 ; agg + b2 (no ReLU)
    gemm_kernel<<<(n + 63) / 64, 256, 0, stream>>>(bufB, W2, bufA, n);
    agg_kernel<<<(n + 7) / 8, 256, 0, stream>>>(bufA, rowptr, col, wgt, dinv, b2, bufB, 0, n);

    // global mean pool
    graph_count_kernel<<<1, 64, 0, stream>>>(batch, cntg, n);
    pool_kernel<<<(n + PCHUNK - 1) / PCHUNK, 128, 0, stream>>>(bufB, batch, out, n);
    div_kernel<<<(out_size + 255) / 256, 256, 0, stream>>>(out, cntg, out_size);
}

// Round 4
// 291.752 us; speedup vs baseline: 2.4863x; 1.2042x over previous
//
#include <hip/hip_runtime.h>

#define D 128
#define N_GRAPHS 64

// ---------------- CSR build ----------------

// count in-degree AND capture each edge's rank among its dst's edges
// (merges the old count_kernel + fill_kernel atomics into one pass)
__global__ void count_rank_kernel(const int* __restrict__ dst, int* __restrict__ cnt,
                                  int* __restrict__ rank, int E) {
    int e = blockIdx.x * blockDim.x + threadIdx.x;
    if (e < E) rank[e] = atomicAdd(&cnt[dst[e]], 1);
}

// parallel scan, phase A: per-1024-chunk exclusive scan + chunk totals; dinv fused
__global__ __launch_bounds__(1024) void scanA_kernel(const int* __restrict__ cnt,
                                                     int* __restrict__ rowptr,
                                                     int* __restrict__ tot,
                                                     float* __restrict__ dinv, int n) {
    __shared__ int swave[16];
    int t = threadIdx.x;
    int lane = t & 63, wave = t >> 6;
    int i = blockIdx.x * 1024 + t;
    int orig = (i < n) ? cnt[i] : 0;
    if (i < n) dinv[i] = rsqrtf((float)(orig + 1));  // deg = in-deg + self loop
    int v = orig;
#pragma unroll
    for (int off = 1; off < 64; off <<= 1) {
        int u = __shfl_up(v, off, 64);
        if (lane >= off) v += u;
    }
    if (lane == 63) swave[wave] = v;
    __syncthreads();
    if (wave == 0) {
        int wv = (lane < 16) ? swave[lane] : 0;
#pragma unroll
        for (int off = 1; off < 16; off <<= 1) {
            int u = __shfl_up(wv, off, 64);
            if (lane >= off) wv += u;
        }
        if (lane < 16) swave[lane] = wv;
    }
    __syncthreads();
    int incl = v + ((wave > 0) ? swave[wave - 1] : 0);
    if (i < n) rowptr[i] = incl - orig;  // chunk-local exclusive
    if (t == 1023) tot[blockIdx.x] = incl;
}

// phase B: add chunk offsets (<=40 totals: serial per-block prefix is cheap)
__global__ __launch_bounds__(1024) void scanB_kernel(int* __restrict__ rowptr,
                                                     const int* __restrict__ tot,
                                                     int n, int nchunks) {
    __shared__ int soff;
    int b = blockIdx.x, t = threadIdx.x;
    if (t == 0) {
        int o = 0;
        for (int j = 0; j < b; ++j) o += tot[j];
        soff = o;
    }
    __syncthreads();
    int i = b * 1024 + t;
    if (i < n) rowptr[i] += soff;
    if (b == 0 && t == 0) {
        int o = 0;
        for (int j = 0; j < nchunks; ++j) o += tot[j];
        rowptr[n] = o;
    }
}

// scatter (col,wgt) packed as 8B — no atomics (rank precomputed)
__global__ void fill_kernel(const int* __restrict__ src, const int* __restrict__ dst,
                            const int* __restrict__ rowptr, const int* __restrict__ rank,
                            unsigned long long* __restrict__ edges,
                            const float* __restrict__ dinv, int E) {
    int e = blockIdx.x * blockDim.x + threadIdx.x;
    if (e < E) {
        int s = src[e], d = dst[e];
        int pos = rowptr[d] + rank[e];
        float w = dinv[s] * dinv[d];
        edges[pos] = (unsigned long long)(unsigned)s |
                     ((unsigned long long)__float_as_uint(w) << 32);
    }
}

// ---------------- dense GEMM: C[M x 128] = A[M x 128] @ W[128 x 128] ----------------
// 64-row x 128-col tile, BK=32, 4x8 acc/thread: 32 FMA per 8 LDS-floats
// (4 FMA/float — balanced against 128 B/cyc LDS vs 128 FMA-lane/cyc VALU)

#define BM 64
#define BK 32

__global__ __launch_bounds__(256) void gemm_kernel(const float* __restrict__ A,
                                                   const float* __restrict__ W,
                                                   float* __restrict__ C, int M) {
    __shared__ float As[BK][BM + 4];  // transposed; +4 keeps b128 alignment, breaks conflicts
    __shared__ float Ws[BK][D];
    int tid = threadIdx.x;
    int tx = tid & 15;   // col group: cols 8*tx..8*tx+7
    int ty = tid >> 4;   // row group: rows 4*ty..4*ty+3
    int row0 = blockIdx.x * BM;
    float acc[4][8];
#pragma unroll
    for (int m = 0; m < 4; ++m)
#pragma unroll
        for (int c = 0; c < 8; ++c) acc[m][c] = 0.f;

    for (int kt = 0; kt < D; kt += BK) {
        // stage A tile (transposed): 512 float4, 2/thread
#pragma unroll
        for (int j = 0; j < 2; ++j) {
            int idx = tid + j * 256;
            int r = idx >> 3, c4 = idx & 7;
            float4 v = make_float4(0.f, 0.f, 0.f, 0.f);
            if (row0 + r < M)
                v = *(const float4*)&A[(size_t)(row0 + r) * D + kt + c4 * 4];
            As[c4 * 4 + 0][r] = v.x;
            As[c4 * 4 + 1][r] = v.y;
            As[c4 * 4 + 2][r] = v.z;
            As[c4 * 4 + 3][r] = v.w;
        }
        // stage W tile: 1024 float4, 4/thread
#pragma unroll
        for (int j = 0; j < 4; ++j) {
            int idx = tid + j * 256;
            int k = idx >> 5, c4 = idx & 31;
            *(float4*)&Ws[k][c4 * 4] = *(const float4*)&W[(size_t)(kt + k) * D + c4 * 4];
        }
        __syncthreads();
#pragma unroll
        for (int k = 0; k < BK; ++k) {
            float4 a  = *(const float4*)&As[k][ty * 4];
            float4 w0 = *(const float4*)&Ws[k][tx * 8];
            float4 w1 = *(const float4*)&Ws[k][tx * 8 + 4];
            float am[4] = {a.x, a.y, a.z, a.w};
            float wv[8] = {w0.x, w0.y, w0.z, w0.w, w1.x, w1.y, w1.z, w1.w};
#pragma unroll
            for (int m = 0; m < 4; ++m)
#pragma unroll
                for (int c = 0; c < 8; ++c) acc[m][c] = fmaf(am[m], wv[c], acc[m][c]);
        }
        __syncthreads();
    }
#pragma unroll
    for (int m = 0; m < 4; ++m) {
        int row = row0 + ty * 4 + m;
        if (row < M) {
            *(float4*)&C[(size_t)row * D + tx * 8] =
                make_float4(acc[m][0], acc[m][1], acc[m][2], acc[m][3]);
            *(float4*)&C[(size_t)row * D + tx * 8 + 4] =
                make_float4(acc[m][4], acc[m][5], acc[m][6], acc[m][7]);
        }
    }
}

// ---------------- aggregation (gather over CSR) + bias (+ReLU) ----------------
// 32-lane group per node (float4/lane = 512B row per load), unroll x8:
// 8 independent 512B gathers in flight per group. Edge loads nontemporal
// (streamed; keep L2 for h rows).

__device__ __forceinline__ void ld_edge(const unsigned long long* p, int& s, float& w) {
    unsigned long long u = __builtin_nontemporal_load(p);
    s = (int)(unsigned)u;
    w = __uint_as_float((unsigned)(u >> 32));
}

__global__ __launch_bounds__(256) void agg_kernel(const float* __restrict__ h,
                                                  const int* __restrict__ rowptr,
                                                  const unsigned long long* __restrict__ edges,
                                                  const float* __restrict__ dinv,
                                                  const float* __restrict__ bias,
                                                  float* __restrict__ out, int relu, int n) {
    int tid = threadIdx.x;
    int lane32 = tid & 31;
    int slot = tid >> 5;  // 0..7
    int node = blockIdx.x * 8 + slot;
    if (node >= n) return;
    const float4* __restrict__ h4 = (const float4*)h;

    float di = dinv[node];
    float ws = di * di;
    float4 self = h4[(size_t)node * 32 + lane32];
    float4 acc;
    acc.x = ws * self.x; acc.y = ws * self.y; acc.z = ws * self.z; acc.w = ws * self.w;

    int k = rowptr[node], end = rowptr[node + 1];
    for (; k + 8 <= end; k += 8) {
        int s0, s1, s2, s3, s4, s5, s6, s7;
        float w0, w1, w2, w3, w4, w5, w6, w7;
        ld_edge(&edges[k + 0], s0, w0); ld_edge(&edges[k + 1], s1, w1);
        ld_edge(&edges[k + 2], s2, w2); ld_edge(&edges[k + 3], s3, w3);
        ld_edge(&edges[k + 4], s4, w4); ld_edge(&edges[k + 5], s5, w5);
        ld_edge(&edges[k + 6], s6, w6); ld_edge(&edges[k + 7], s7, w7);
        float4 v0 = h4[(size_t)s0 * 32 + lane32];
        float4 v1 = h4[(size_t)s1 * 32 + lane32];
        float4 v2 = h4[(size_t)s2 * 32 + lane32];
        float4 v3 = h4[(size_t)s3 * 32 + lane32];
        float4 v4 = h4[(size_t)s4 * 32 + lane32];
        float4 v5 = h4[(size_t)s5 * 32 + lane32];
        float4 v6 = h4[(size_t)s6 * 32 + lane32];
        float4 v7 = h4[(size_t)s7 * 32 + lane32];
        acc.x = fmaf(w0, v0.x, acc.x); acc.y = fmaf(w0, v0.y, acc.y);
        acc.z = fmaf(w0, v0.z, acc.z); acc.w = fmaf(w0, v0.w, acc.w);
        acc.x = fmaf(w1, v1.x, acc.x); acc.y = fmaf(w1, v1.y, acc.y);
        acc.z = fmaf(w1, v1.z, acc.z); acc.w = fmaf(w1, v1.w, acc.w);
        acc.x = fmaf(w2, v2.x, acc.x); acc.y = fmaf(w2, v2.y, acc.y);
        acc.z = fmaf(w2, v2.z, acc.z); acc.w = fmaf(w2, v2.w, acc.w);
        acc.x = fmaf(w3, v3.x, acc.x); acc.y = fmaf(w3, v3.y, acc.y);
        acc.z = fmaf(w3, v3.z, acc.z); acc.w = fmaf(w3, v3.w, acc.w);
        acc.x = fmaf(w4, v4.x, acc.x); acc.y = fmaf(w4, v4.y, acc.y);
        acc.z = fmaf(w4, v4.z, acc.z); acc.w = fmaf(w4, v4.w, acc.w);
        acc.x = fmaf(w5, v5.x, acc.x); acc.y = fmaf(w5, v5.y, acc.y);
        acc.z = fmaf(w5, v5.z, acc.z); acc.w = fmaf(w5, v5.w, acc.w);
        acc.x = fmaf(w6, v6.x, acc.x); acc.y = fmaf(w6, v6.y, acc.y);
        acc.z = fmaf(w6, v6.z, acc.z); acc.w = fmaf(w6, v6.w, acc.w);
        acc.x = fmaf(w7, v7.x, acc.x); acc.y = fmaf(w7, v7.y, acc.y);
        acc.z = fmaf(w7, v7.z, acc.z); acc.w = fmaf(w7, v7.w, acc.w);
    }
    if (k + 4 <= end) {
        int s0, s1, s2, s3;
        float w0, w1, w2, w3;
        ld_edge(&edges[k + 0], s0, w0); ld_edge(&edges[k + 1], s1, w1);
        ld_edge(&edges[k + 2], s2, w2); ld_edge(&edges[k + 3], s3, w3);
        float4 v0 = h4[(size_t)s0 * 32 + lane32];
        float4 v1 = h4[(size_t)s1 * 32 + lane32];
        float4 v2 = h4[(size_t)s2 * 32 + lane32];
        float4 v3 = h4[(size_t)s3 * 32 + lane32];
        acc.x = fmaf(w0, v0.x, acc.x); acc.y = fmaf(w0, v0.y, acc.y);
        acc.z = fmaf(w0, v0.z, acc.z); acc.w = fmaf(w0, v0.w, acc.w);
        acc.x = fmaf(w1, v1.x, acc.x); acc.y = fmaf(w1, v1.y, acc.y);
        acc.z = fmaf(w1, v1.z, acc.z); acc.w = fmaf(w1, v1.w, acc.w);
        acc.x = fmaf(w2, v2.x, acc.x); acc.y = fmaf(w2, v2.y, acc.y);
        acc.z = fmaf(w2, v2.z, acc.z); acc.w = fmaf(w2, v2.w, acc.w);
        acc.x = fmaf(w3, v3.x, acc.x); acc.y = fmaf(w3, v3.y, acc.y);
        acc.z = fmaf(w3, v3.z, acc.z); acc.w = fmaf(w3, v3.w, acc.w);
        k += 4;
    }
    for (; k < end; ++k) {
        int s; float w;
        ld_edge(&edges[k], s, w);
        float4 v = h4[(size_t)s * 32 + lane32];
        acc.x = fmaf(w, v.x, acc.x); acc.y = fmaf(w, v.y, acc.y);
        acc.z = fmaf(w, v.z, acc.z); acc.w = fmaf(w, v.w, acc.w);
    }

    float4 b4 = ((const float4*)bias)[lane32];
    acc.x += b4.x; acc.y += b4.y; acc.z += b4.z; acc.w += b4.w;
    if (relu) {
        acc.x = fmaxf(acc.x, 0.f); acc.y = fmaxf(acc.y, 0.f);
        acc.z = fmaxf(acc.z, 0.f); acc.w = fmaxf(acc.w, 0.f);
    }
    ((float4*)out)[(size_t)node * 32 + lane32] = acc;
}

// ---------------- pooling ----------------

// batch is sorted: per-graph 1/count via binary search (no atomics)
__global__ void graph_count_kernel(const int* __restrict__ batch, float* __restrict__ rinvg, int n) {
    int g = threadIdx.x;
    if (g >= N_GRAPHS) return;
    int lo = 0, hi = n;
    while (lo < hi) { int mid = (lo + hi) >> 1; if (batch[mid] < g) lo = mid + 1; else hi = mid; }
    int lb0 = lo;
    int g1 = g + 1;
    lo = 0; hi = n;
    while (lo < hi) { int mid = (lo + hi) >> 1; if (batch[mid] < g1) lo = mid + 1; else hi = mid; }
    int c = lo - lb0;
    rinvg[g] = 1.0f / (float)max(c, 1);
}

// 32-lane group x float4 per lane; 32 nodes per group; scale by rinv at flush
#define PNODES 32
__global__ __launch_bounds__(256) void pool_kernel(const float* __restrict__ h,
                                                   const int* __restrict__ batch,
                                                   const float* __restrict__ rinvg,
                                                   float* __restrict__ out, int n) {
    int lane = threadIdx.x & 31;
    int sub = threadIdx.x >> 5;  // 0..7
    int base = (blockIdx.x * 8 + sub) * PNODES;
    if (base >= n) return;
    int end = min(base + PNODES, n);
    const float4* __restrict__ h4 = (const float4*)h;
    int cur = batch[base];
    float4 acc = make_float4(0.f, 0.f, 0.f, 0.f);
    for (int i = base; i < end; ++i) {
        int g = batch[i];
        if (g != cur) {
            float r = rinvg[cur];
            float* o = &out[cur * D + lane * 4];
            atomicAdd(&o[0], acc.x * r); atomicAdd(&o[1], acc.y * r);
            atomicAdd(&o[2], acc.z * r); atomicAdd(&o[3], acc.w * r);
            acc = make_float4(0.f, 0.f, 0.f, 0.f);
            cur = g;
        }
        float4 v = h4[(size_t)i * 32 + lane];
        acc.x += v.x; acc.y += v.y; acc.z += v.z; acc.w += v.w;
    }
    float r = rinvg[cur];
    float* o = &out[cur * D + lane * 4];
    atomicAdd(&o[0], acc.x * r); atomicAdd(&o[1], acc.y * r);
    atomicAdd(&o[2], acc.z * r); atomicAdd(&o[3], acc.w * r);
}

// ---------------- launcher ----------------

extern "C" void kernel_launch(void* const* d_in, const int* in_sizes, int n_in,
                              void* d_out, int out_size, void* d_ws, size_t ws_size,
                              hipStream_t stream) {
    const float* x  = (const float*)d_in[0];
    const int*   ei = (const int*)d_in[1];
    const int*   batch = (const int*)d_in[2];
    const float* W1 = (const float*)d_in[3];
    const float* b1 = (const float*)d_in[4];
    const float* W2 = (const float*)d_in[5];
    const float* b2 = (const float*)d_in[6];
    float* out = (float*)d_out;

    const int n = in_sizes[2];       // 40000 nodes
    const int E = in_sizes[1] / 2;   // 640000 edges
    const int* src = ei;             // edge_index[0] = message sources
    const int* dst = ei + E;         // edge_index[1] = aggregation targets

    // workspace carve-up (256B aligned)
    char* ws = (char*)d_ws;
    size_t off = 0;
    auto carve = [&](size_t bytes) {
        size_t o = off;
        off = (off + bytes + 255) & ~(size_t)255;
        return (void*)(ws + o);
    };
    int*   cnt    = (int*)carve((size_t)n * 4);
    int*   rowptr = (int*)carve((size_t)(n + 1) * 4);
    float* dinv   = (float*)carve((size_t)n * 4);
    unsigned long long* edges = (unsigned long long*)carve((size_t)E * 8);
    float* bufA   = (float*)carve((size_t)n * D * 4);
    float* bufB   = (float*)carve((size_t)n * D * 4);
    int*   tot    = (int*)carve(64 * 4);
    float* rinvg  = (float*)carve(N_GRAPHS * 4);
    // rank is dead after fill_kernel; bufA is first written after fill -> alias
    int*   rank   = (int*)bufA;
    (void)ws_size;

    const int nchunks = (n + 1023) >> 10;

    // zero-init (ws/out are poisoned 0xAA before every call)
    hipMemsetAsync(cnt, 0, (size_t)n * 4, stream);
    hipMemsetAsync(out, 0, (size_t)out_size * 4, stream);

    // CSR build (shared by both layers)
    count_rank_kernel<<<(E + 255) / 256, 256, 0, stream>>>(dst, cnt, rank, E);
    scanA_kernel<<<nchunks, 1024, 0, stream>>>(cnt, rowptr, tot, dinv, n);
    scanB_kernel<<<nchunks, 1024, 0, stream>>>(rowptr, tot, n, nchunks);
    fill_kernel<<<(E + 255) / 256, 256, 0, stream>>>(src, dst, rowptr, rank, edges, dinv, E);

    // layer 1: h1 = x @ W1 ; agg + b1 + ReLU
    gemm_kernel<<<(n + BM - 1) / BM, 256, 0, stream>>>(x, W1, bufA, n);
    agg_kernel<<<(n + 7) / 8, 256, 0, stream>>>(bufA, rowptr, edges, dinv, b1, bufB, 1, n);

    // layer 2: h2 = h1' @ W2 ; agg + b2 (no ReLU)
    gemm_kernel<<<(n + BM - 1) / BM, 256, 0, stream>>>(bufB, W2, bufA, n);
    agg_kernel<<<(n + 7) / 8, 256, 0, stream>>>(bufA, rowptr, edges, dinv, b2, bufB, 0, n);

    // global mean pool (divide folded in via rinvg)
    graph_count_kernel<<<1, 64, 0, stream>>>(batch, rinvg, n);
    pool_kernel<<<(n + 8 * PNODES - 1) / (8 * PNODES), 256, 0, stream>>>(bufB, batch, rinvg, out, n);
}

// Round 5
// 259.193 us; speedup vs baseline: 2.7986x; 1.1256x over previous
//
#include <hip/hip_runtime.h>

#define D 128
#define N_GRAPHS 64

typedef unsigned int uint32;

// bf16 helpers: unpack (dword holds 2 bf16: low = elem 2i, high = elem 2i+1)
__device__ __forceinline__ float bl(uint32 u) { return __uint_as_float(u << 16); }
__device__ __forceinline__ float bh(uint32 u) { return __uint_as_float(u & 0xFFFF0000u); }
// pack two floats to bf16 pair with round-to-nearest-even
__device__ __forceinline__ uint32 bf16pair(float a, float b) {
    uint32 ua = __float_as_uint(a);
    ua = (ua + 0x7fff + ((ua >> 16) & 1)) >> 16;
    uint32 ub = __float_as_uint(b);
    ub = (ub + 0x7fff + ((ub >> 16) & 1)) & 0xFFFF0000u;
    return ua | ub;
}

// ---------------- CSR build ----------------

// count in-degree AND capture each edge's rank among its dst's edges
__global__ void count_rank_kernel(const int* __restrict__ dst, int* __restrict__ cnt,
                                  int* __restrict__ rank, int E) {
    int e = blockIdx.x * blockDim.x + threadIdx.x;
    if (e < E) rank[e] = atomicAdd(&cnt[dst[e]], 1);
}

// parallel scan, phase A: per-1024-chunk exclusive scan + chunk totals; dinv fused
__global__ __launch_bounds__(1024) void scanA_kernel(const int* __restrict__ cnt,
                                                     int* __restrict__ rowptr,
                                                     int* __restrict__ tot,
                                                     float* __restrict__ dinv, int n) {
    __shared__ int swave[16];
    int t = threadIdx.x;
    int lane = t & 63, wave = t >> 6;
    int i = blockIdx.x * 1024 + t;
    int orig = (i < n) ? cnt[i] : 0;
    if (i < n) dinv[i] = rsqrtf((float)(orig + 1));  // deg = in-deg + self loop
    int v = orig;
#pragma unroll
    for (int off = 1; off < 64; off <<= 1) {
        int u = __shfl_up(v, off, 64);
        if (lane >= off) v += u;
    }
    if (lane == 63) swave[wave] = v;
    __syncthreads();
    if (wave == 0) {
        int wv = (lane < 16) ? swave[lane] : 0;
#pragma unroll
        for (int off = 1; off < 16; off <<= 1) {
            int u = __shfl_up(wv, off, 64);
            if (lane >= off) wv += u;
        }
        if (lane < 16) swave[lane] = wv;
    }
    __syncthreads();
    int incl = v + ((wave > 0) ? swave[wave - 1] : 0);
    if (i < n) rowptr[i] = incl - orig;  // chunk-local exclusive
    if (t == 1023) tot[blockIdx.x] = incl;
}

// phase B: add chunk offsets (<=40 totals: serial per-block prefix is cheap)
__global__ __launch_bounds__(1024) void scanB_kernel(int* __restrict__ rowptr,
                                                     const int* __restrict__ tot,
                                                     int n, int nchunks) {
    __shared__ int soff;
    int b = blockIdx.x, t = threadIdx.x;
    if (t == 0) {
        int o = 0;
        for (int j = 0; j < b; ++j) o += tot[j];
        soff = o;
    }
    __syncthreads();
    int i = b * 1024 + t;
    if (i < n) rowptr[i] += soff;
    if (b == 0 && t == 0) {
        int o = 0;
        for (int j = 0; j < nchunks; ++j) o += tot[j];
        rowptr[n] = o;
    }
}

// scatter (col,wgt) packed as 8B — no atomics (rank precomputed)
__global__ void fill_kernel(const int* __restrict__ src, const int* __restrict__ dst,
                            const int* __restrict__ rowptr, const int* __restrict__ rank,
                            unsigned long long* __restrict__ edges,
                            const float* __restrict__ dinv, int E) {
    int e = blockIdx.x * blockDim.x + threadIdx.x;
    if (e < E) {
        int s = src[e], d = dst[e];
        int pos = rowptr[d] + rank[e];
        float w = dinv[s] * dinv[d];
        edges[pos] = (unsigned long long)(unsigned)s |
                     ((unsigned long long)__float_as_uint(w) << 32);
    }
}

// ---------------- dense GEMM: Hb[M x 128](bf16) = A[M x 128](f32) @ W[128 x 128] ----
// 64-row x 128-col tile, BK=32, 4x8 acc/thread; bf16 epilogue (halves write traffic,
// and bf16 rows halve the downstream gather traffic in agg)

#define BM 64
#define BK 32

__global__ __launch_bounds__(256) void gemm_kernel(const float* __restrict__ A,
                                                   const float* __restrict__ W,
                                                   uint32* __restrict__ hb, int M) {
    __shared__ float As[BK][BM + 4];
    __shared__ float Ws[BK][D];
    int tid = threadIdx.x;
    int tx = tid & 15;   // col group: cols 8*tx..8*tx+7
    int ty = tid >> 4;   // row group: rows 4*ty..4*ty+3
    int row0 = blockIdx.x * BM;
    float acc[4][8];
#pragma unroll
    for (int m = 0; m < 4; ++m)
#pragma unroll
        for (int c = 0; c < 8; ++c) acc[m][c] = 0.f;

    for (int kt = 0; kt < D; kt += BK) {
#pragma unroll
        for (int j = 0; j < 2; ++j) {
            int idx = tid + j * 256;
            int r = idx >> 3, c4 = idx & 7;
            float4 v = make_float4(0.f, 0.f, 0.f, 0.f);
            if (row0 + r < M)
                v = *(const float4*)&A[(size_t)(row0 + r) * D + kt + c4 * 4];
            As[c4 * 4 + 0][r] = v.x;
            As[c4 * 4 + 1][r] = v.y;
            As[c4 * 4 + 2][r] = v.z;
            As[c4 * 4 + 3][r] = v.w;
        }
#pragma unroll
        for (int j = 0; j < 4; ++j) {
            int idx = tid + j * 256;
            int k = idx >> 5, c4 = idx & 31;
            *(float4*)&Ws[k][c4 * 4] = *(const float4*)&W[(size_t)(kt + k) * D + c4 * 4];
        }
        __syncthreads();
#pragma unroll
        for (int k = 0; k < BK; ++k) {
            float4 a  = *(const float4*)&As[k][ty * 4];
            float4 w0 = *(const float4*)&Ws[k][tx * 8];
            float4 w1 = *(const float4*)&Ws[k][tx * 8 + 4];
            float am[4] = {a.x, a.y, a.z, a.w};
            float wv[8] = {w0.x, w0.y, w0.z, w0.w, w1.x, w1.y, w1.z, w1.w};
#pragma unroll
            for (int m = 0; m < 4; ++m)
#pragma unroll
                for (int c = 0; c < 8; ++c) acc[m][c] = fmaf(am[m], wv[c], acc[m][c]);
        }
        __syncthreads();
    }
#pragma unroll
    for (int m = 0; m < 4; ++m) {
        int row = row0 + ty * 4 + m;
        if (row < M) {
            uint4 o;
            o.x = bf16pair(acc[m][0], acc[m][1]);
            o.y = bf16pair(acc[m][2], acc[m][3]);
            o.z = bf16pair(acc[m][4], acc[m][5]);
            o.w = bf16pair(acc[m][6], acc[m][7]);
            *(uint4*)&hb[(size_t)row * 64 + tx * 4] = o;  // 128 bf16 = 64 dwords/row
        }
    }
}

// ---------------- aggregation (gather over CSR) + bias (+ReLU) ----------------
// bf16 rows: 32-lane group per node, uint2 (8B = 4 bf16) per lane = 256B row/load.
// Unroll x8 -> 8 independent 256B gathers in flight per group. Edge loads plain
// (sequential 64B lines with 8x reuse — they WANT L2; nt was a regression).

__global__ __launch_bounds__(256) void agg_kernel(const uint32* __restrict__ hb,
                                                  const int* __restrict__ rowptr,
                                                  const unsigned long long* __restrict__ edges,
                                                  const float* __restrict__ dinv,
                                                  const float* __restrict__ bias,
                                                  float* __restrict__ out, int relu, int n) {
    int tid = threadIdx.x;
    int lane32 = tid & 31;   // features 4*lane32 .. 4*lane32+3
    int slot = tid >> 5;     // 0..7
    int node = blockIdx.x * 8 + slot;
    if (node >= n) return;
    const uint2* __restrict__ h2 = (const uint2*)hb;  // 32 uint2 per row

    float di = dinv[node];
    float ws = di * di;
    uint2 su = h2[(size_t)node * 32 + lane32];
    float a0 = ws * bl(su.x), a1 = ws * bh(su.x);
    float a2 = ws * bl(su.y), a3 = ws * bh(su.y);

    int k = rowptr[node], end = rowptr[node + 1];
    for (; k + 8 <= end; k += 8) {
        uint2 v[8];
        float w[8];
#pragma unroll
        for (int j = 0; j < 8; ++j) {
            unsigned long long u = edges[k + j];
            int s = (int)(unsigned)u;
            w[j] = __uint_as_float((unsigned)(u >> 32));
            v[j] = h2[(size_t)s * 32 + lane32];
        }
#pragma unroll
        for (int j = 0; j < 8; ++j) {
            a0 = fmaf(w[j], bl(v[j].x), a0);
            a1 = fmaf(w[j], bh(v[j].x), a1);
            a2 = fmaf(w[j], bl(v[j].y), a2);
            a3 = fmaf(w[j], bh(v[j].y), a3);
        }
    }
    for (; k < end; ++k) {
        unsigned long long u = edges[k];
        int s = (int)(unsigned)u;
        float w = __uint_as_float((unsigned)(u >> 32));
        uint2 v = h2[(size_t)s * 32 + lane32];
        a0 = fmaf(w, bl(v.x), a0);
        a1 = fmaf(w, bh(v.x), a1);
        a2 = fmaf(w, bl(v.y), a2);
        a3 = fmaf(w, bh(v.y), a3);
    }

    float4 b4 = ((const float4*)bias)[lane32];
    a0 += b4.x; a1 += b4.y; a2 += b4.z; a3 += b4.w;
    if (relu) {
        a0 = fmaxf(a0, 0.f); a1 = fmaxf(a1, 0.f);
        a2 = fmaxf(a2, 0.f); a3 = fmaxf(a3, 0.f);
    }
    ((float4*)out)[(size_t)node * 32 + lane32] = make_float4(a0, a1, a2, a3);
}

// ---------------- pooling ----------------

// batch is sorted: per-graph 1/count via binary search (no atomics)
__global__ void graph_count_kernel(const int* __restrict__ batch, float* __restrict__ rinvg, int n) {
    int g = threadIdx.x;
    if (g >= N_GRAPHS) return;
    int lo = 0, hi = n;
    while (lo < hi) { int mid = (lo + hi) >> 1; if (batch[mid] < g) lo = mid + 1; else hi = mid; }
    int lb0 = lo;
    int g1 = g + 1;
    lo = 0; hi = n;
    while (lo < hi) { int mid = (lo + hi) >> 1; if (batch[mid] < g1) lo = mid + 1; else hi = mid; }
    int c = lo - lb0;
    rinvg[g] = 1.0f / (float)max(c, 1);
}

// 32-lane group x float4 per lane; 32 nodes per group; scale by rinv at flush
#define PNODES 32
__global__ __launch_bounds__(256) void pool_kernel(const float* __restrict__ h,
                                                   const int* __restrict__ batch,
                                                   const float* __restrict__ rinvg,
                                                   float* __restrict__ out, int n) {
    int lane = threadIdx.x & 31;
    int sub = threadIdx.x >> 5;  // 0..7
    int base = (blockIdx.x * 8 + sub) * PNODES;
    if (base >= n) return;
    int end = min(base + PNODES, n);
    const float4* __restrict__ h4 = (const float4*)h;
    int cur = batch[base];
    float4 acc = make_float4(0.f, 0.f, 0.f, 0.f);
    for (int i = base; i < end; ++i) {
        int g = batch[i];
        if (g != cur) {
            float r = rinvg[cur];
            float* o = &out[cur * D + lane * 4];
            atomicAdd(&o[0], acc.x * r); atomicAdd(&o[1], acc.y * r);
            atomicAdd(&o[2], acc.z * r); atomicAdd(&o[3], acc.w * r);
            acc = make_float4(0.f, 0.f, 0.f, 0.f);
            cur = g;
        }
        float4 v = h4[(size_t)i * 32 + lane];
        acc.x += v.x; acc.y += v.y; acc.z += v.z; acc.w += v.w;
    }
    float r = rinvg[cur];
    float* o = &out[cur * D + lane * 4];
    atomicAdd(&o[0], acc.x * r); atomicAdd(&o[1], acc.y * r);
    atomicAdd(&o[2], acc.z * r); atomicAdd(&o[3], acc.w * r);
}

// ---------------- launcher ----------------

extern "C" void kernel_launch(void* const* d_in, const int* in_sizes, int n_in,
                              void* d_out, int out_size, void* d_ws, size_t ws_size,
                              hipStream_t stream) {
    const float* x  = (const float*)d_in[0];
    const int*   ei = (const int*)d_in[1];
    const int*   batch = (const int*)d_in[2];
    const float* W1 = (const float*)d_in[3];
    const float* b1 = (const float*)d_in[4];
    const float* W2 = (const float*)d_in[5];
    const float* b2 = (const float*)d_in[6];
    float* out = (float*)d_out;

    const int n = in_sizes[2];       // 40000 nodes
    const int E = in_sizes[1] / 2;   // 640000 edges
    const int* src = ei;             // edge_index[0] = message sources
    const int* dst = ei + E;         // edge_index[1] = aggregation targets

    // workspace carve-up (256B aligned)
    char* ws = (char*)d_ws;
    size_t off = 0;
    auto carve = [&](size_t bytes) {
        size_t o = off;
        off = (off + bytes + 255) & ~(size_t)255;
        return (void*)(ws + o);
    };
    int*    cnt    = (int*)carve((size_t)n * 4);
    int*    rowptr = (int*)carve((size_t)(n + 1) * 4);
    float*  dinv   = (float*)carve((size_t)n * 4);
    unsigned long long* edges = (unsigned long long*)carve((size_t)E * 8);
    uint32* hb     = (uint32*)carve((size_t)n * D * 2);   // bf16 feature rows
    float*  bufB   = (float*)carve((size_t)n * D * 4);    // fp32 agg outputs
    int*    tot    = (int*)carve(64 * 4);
    float*  rinvg  = (float*)carve(N_GRAPHS * 4);
    // rank (E*4 = 2.56MB) is dead after fill; hb (10.24MB) first written by gemm1 -> alias
    int*    rank   = (int*)hb;
    (void)ws_size;

    const int nchunks = (n + 1023) >> 10;

    // zero-init (ws/out are poisoned 0xAA before every call)
    hipMemsetAsync(cnt, 0, (size_t)n * 4, stream);
    hipMemsetAsync(out, 0, (size_t)out_size * 4, stream);

    // CSR build (shared by both layers)
    count_rank_kernel<<<(E + 255) / 256, 256, 0, stream>>>(dst, cnt, rank, E);
    scanA_kernel<<<nchunks, 1024, 0, stream>>>(cnt, rowptr, tot, dinv, n);
    scanB_kernel<<<nchunks, 1024, 0, stream>>>(rowptr, tot, n, nchunks);
    fill_kernel<<<(E + 255) / 256, 256, 0, stream>>>(src, dst, rowptr, rank, edges, dinv, E);

    // layer 1: hb = bf16(x @ W1) ; agg + b1 + ReLU -> bufB (fp32)
    gemm_kernel<<<(n + BM - 1) / BM, 256, 0, stream>>>(x, W1, hb, n);
    agg_kernel<<<(n + 7) / 8, 256, 0, stream>>>(hb, rowptr, edges, dinv, b1, bufB, 1, n);

    // layer 2: hb = bf16(bufB @ W2) ; agg + b2 -> bufB (gemm2 input dead by then)
    gemm_kernel<<<(n + BM - 1) / BM, 256, 0, stream>>>(bufB, W2, hb, n);
    agg_kernel<<<(n + 7) / 8, 256, 0, stream>>>(hb, rowptr, edges, dinv, b2, bufB, 0, n);

    // global mean pool (divide folded in via rinvg)
    graph_count_kernel<<<1, 64, 0, stream>>>(batch, rinvg, n);
    pool_kernel<<<(n + 8 * PNODES - 1) / (8 * PNODES), 256, 0, stream>>>(bufB, batch, rinvg, out, n);
}

// Round 6
// 252.064 us; speedup vs baseline: 2.8778x; 1.0283x over previous
//
#include <hip/hip_runtime.h>

#define D 128
#define N_GRAPHS 64

typedef unsigned int uint32;

// bf16 helpers: unpack (dword holds 2 bf16: low = elem 2i, high = elem 2i+1)
__device__ __forceinline__ float bl(uint32 u) { return __uint_as_float(u << 16); }
__device__ __forceinline__ float bh(uint32 u) { return __uint_as_float(u & 0xFFFF0000u); }
// pack two floats to bf16 pair with round-to-nearest-even
__device__ __forceinline__ uint32 bf16pair(float a, float b) {
    uint32 ua = __float_as_uint(a);
    ua = (ua + 0x7fff + ((ua >> 16) & 1)) >> 16;
    uint32 ub = __float_as_uint(b);
    ub = (ub + 0x7fff + ((ub >> 16) & 1)) & 0xFFFF0000u;
    return ua | ub;
}

// ---------------- CSR build ----------------

// count in-degree AND capture each edge's rank among its dst's edges
__global__ void count_rank_kernel(const int* __restrict__ dst, int* __restrict__ cnt,
                                  int* __restrict__ rank, int E) {
    int e = blockIdx.x * blockDim.x + threadIdx.x;
    if (e < E) rank[e] = atomicAdd(&cnt[dst[e]], 1);
}

// parallel scan, phase A: per-1024-chunk exclusive scan + chunk totals.
// Fused: dinv, and the self-loop term of the pooled-coefficient matrix
// c[j][batch[j]] = dinv_j^2 (c pre-zeroed; plain store, fill's atomics run later)
__global__ __launch_bounds__(1024) void scanA_kernel(const int* __restrict__ cnt,
                                                     int* __restrict__ rowptr,
                                                     int* __restrict__ tot,
                                                     float* __restrict__ dinv,
                                                     float* __restrict__ c,
                                                     const int* __restrict__ batch, int n) {
    __shared__ int swave[16];
    int t = threadIdx.x;
    int lane = t & 63, wave = t >> 6;
    int i = blockIdx.x * 1024 + t;
    int orig = (i < n) ? cnt[i] : 0;
    if (i < n) {
        float dv = rsqrtf((float)(orig + 1));  // deg = in-deg + self loop
        dinv[i] = dv;
        c[(size_t)i * N_GRAPHS + batch[i]] = dv * dv;  // self-loop contribution
    }
    int v = orig;
#pragma unroll
    for (int off = 1; off < 64; off <<= 1) {
        int u = __shfl_up(v, off, 64);
        if (lane >= off) v += u;
    }
    if (lane == 63) swave[wave] = v;
    __syncthreads();
    if (wave == 0) {
        int wv = (lane < 16) ? swave[lane] : 0;
#pragma unroll
        for (int off = 1; off < 16; off <<= 1) {
            int u = __shfl_up(wv, off, 64);
            if (lane >= off) wv += u;
        }
        if (lane < 16) swave[lane] = wv;
    }
    __syncthreads();
    int incl = v + ((wave > 0) ? swave[wave - 1] : 0);
    if (i < n) rowptr[i] = incl - orig;  // chunk-local exclusive
    if (t == 1023) tot[blockIdx.x] = incl;
}

// phase B: add chunk offsets (<=40 totals: serial per-block prefix is cheap)
__global__ __launch_bounds__(1024) void scanB_kernel(int* __restrict__ rowptr,
                                                     const int* __restrict__ tot,
                                                     int n, int nchunks) {
    __shared__ int soff;
    int b = blockIdx.x, t = threadIdx.x;
    if (t == 0) {
        int o = 0;
        for (int j = 0; j < b; ++j) o += tot[j];
        soff = o;
    }
    __syncthreads();
    int i = b * 1024 + t;
    if (i < n) rowptr[i] += soff;
    if (b == 0 && t == 0) {
        int o = 0;
        for (int j = 0; j < nchunks; ++j) o += tot[j];
        rowptr[n] = o;
    }
}

// scatter (col,wgt) packed as 8B (no atomics — rank precomputed), and
// accumulate the edge term of c: c[src][batch[dst]] += w  (640k atomics
// over 2.56M slots — near-zero same-address contention)
__global__ void fill_kernel(const int* __restrict__ src, const int* __restrict__ dst,
                            const int* __restrict__ rowptr, const int* __restrict__ rank,
                            unsigned long long* __restrict__ edges,
                            const float* __restrict__ dinv,
                            float* __restrict__ c, const int* __restrict__ batch, int E) {
    int e = blockIdx.x * blockDim.x + threadIdx.x;
    if (e < E) {
        int s = src[e], d = dst[e];
        int pos = rowptr[d] + rank[e];
        float w = dinv[s] * dinv[d];
        edges[pos] = (unsigned long long)(unsigned)s |
                     ((unsigned long long)__float_as_uint(w) << 32);
        atomicAdd(&c[(size_t)s * N_GRAPHS + batch[d]], w);
    }
}

// ---------------- dense GEMM: Hb[M x 128](bf16) = A[M x 128](f32) @ W[128 x 128] ----

#define BM 64
#define BK 32

__global__ __launch_bounds__(256) void gemm_kernel(const float* __restrict__ A,
                                                   const float* __restrict__ W,
                                                   uint32* __restrict__ hb, int M) {
    __shared__ float As[BK][BM + 4];
    __shared__ float Ws[BK][D];
    int tid = threadIdx.x;
    int tx = tid & 15;   // col group: cols 8*tx..8*tx+7
    int ty = tid >> 4;   // row group: rows 4*ty..4*ty+3
    int row0 = blockIdx.x * BM;
    float acc[4][8];
#pragma unroll
    for (int m = 0; m < 4; ++m)
#pragma unroll
        for (int cc = 0; cc < 8; ++cc) acc[m][cc] = 0.f;

    for (int kt = 0; kt < D; kt += BK) {
#pragma unroll
        for (int j = 0; j < 2; ++j) {
            int idx = tid + j * 256;
            int r = idx >> 3, c4 = idx & 7;
            float4 v = make_float4(0.f, 0.f, 0.f, 0.f);
            if (row0 + r < M)
                v = *(const float4*)&A[(size_t)(row0 + r) * D + kt + c4 * 4];
            As[c4 * 4 + 0][r] = v.x;
            As[c4 * 4 + 1][r] = v.y;
            As[c4 * 4 + 2][r] = v.z;
            As[c4 * 4 + 3][r] = v.w;
        }
#pragma unroll
        for (int j = 0; j < 4; ++j) {
            int idx = tid + j * 256;
            int k = idx >> 5, c4 = idx & 31;
            *(float4*)&Ws[k][c4 * 4] = *(const float4*)&W[(size_t)(kt + k) * D + c4 * 4];
        }
        __syncthreads();
#pragma unroll
        for (int k = 0; k < BK; ++k) {
            float4 a  = *(const float4*)&As[k][ty * 4];
            float4 w0 = *(const float4*)&Ws[k][tx * 8];
            float4 w1 = *(const float4*)&Ws[k][tx * 8 + 4];
            float am[4] = {a.x, a.y, a.z, a.w};
            float wv[8] = {w0.x, w0.y, w0.z, w0.w, w1.x, w1.y, w1.z, w1.w};
#pragma unroll
            for (int m = 0; m < 4; ++m)
#pragma unroll
                for (int cc = 0; cc < 8; ++cc) acc[m][cc] = fmaf(am[m], wv[cc], acc[m][cc]);
        }
        __syncthreads();
    }
#pragma unroll
    for (int m = 0; m < 4; ++m) {
        int row = row0 + ty * 4 + m;
        if (row < M) {
            uint4 o;
            o.x = bf16pair(acc[m][0], acc[m][1]);
            o.y = bf16pair(acc[m][2], acc[m][3]);
            o.z = bf16pair(acc[m][4], acc[m][5]);
            o.w = bf16pair(acc[m][6], acc[m][7]);
            *(uint4*)&hb[(size_t)row * 64 + tx * 4] = o;  // 128 bf16 = 64 dwords/row
        }
    }
}

// ---------------- aggregation (gather over CSR) + bias + ReLU ----------------
// bf16 rows: 32-lane group per node, uint2 (8B = 4 bf16) per lane = 256B row/load.

__global__ __launch_bounds__(256) void agg_kernel(const uint32* __restrict__ hb,
                                                  const int* __restrict__ rowptr,
                                                  const unsigned long long* __restrict__ edges,
                                                  const float* __restrict__ dinv,
                                                  const float* __restrict__ bias,
                                                  float* __restrict__ out, int n) {
    int tid = threadIdx.x;
    int lane32 = tid & 31;   // features 4*lane32 .. 4*lane32+3
    int slot = tid >> 5;     // 0..7
    int node = blockIdx.x * 8 + slot;
    if (node >= n) return;
    const uint2* __restrict__ h2 = (const uint2*)hb;  // 32 uint2 per row

    float di = dinv[node];
    float ws = di * di;
    uint2 su = h2[(size_t)node * 32 + lane32];
    float a0 = ws * bl(su.x), a1 = ws * bh(su.x);
    float a2 = ws * bl(su.y), a3 = ws * bh(su.y);

    int k = rowptr[node], end = rowptr[node + 1];
    for (; k + 8 <= end; k += 8) {
        uint2 v[8];
        float w[8];
#pragma unroll
        for (int j = 0; j < 8; ++j) {
            unsigned long long u = edges[k + j];
            int s = (int)(unsigned)u;
            w[j] = __uint_as_float((unsigned)(u >> 32));
            v[j] = h2[(size_t)s * 32 + lane32];
        }
#pragma unroll
        for (int j = 0; j < 8; ++j) {
            a0 = fmaf(w[j], bl(v[j].x), a0);
            a1 = fmaf(w[j], bh(v[j].x), a1);
            a2 = fmaf(w[j], bl(v[j].y), a2);
            a3 = fmaf(w[j], bh(v[j].y), a3);
        }
    }
    for (; k < end; ++k) {
        unsigned long long u = edges[k];
        int s = (int)(unsigned)u;
        float w = __uint_as_float((unsigned)(u >> 32));
        uint2 v = h2[(size_t)s * 32 + lane32];
        a0 = fmaf(w, bl(v.x), a0);
        a1 = fmaf(w, bh(v.x), a1);
        a2 = fmaf(w, bl(v.y), a2);
        a3 = fmaf(w, bh(v.y), a3);
    }

    float4 b4 = ((const float4*)bias)[lane32];
    a0 = fmaxf(a0 + b4.x, 0.f);
    a1 = fmaxf(a1 + b4.y, 0.f);
    a2 = fmaxf(a2 + b4.z, 0.f);
    a3 = fmaxf(a3 + b4.w, 0.f);
    ((float4*)out)[(size_t)node * 32 + lane32] = make_float4(a0, a1, a2, a3);
}

// ---------------- pooled layer 2: out = rinv * (c^T H1) W2 + b2 ----------------

// batch is sorted: per-graph 1/count via binary search; 0 flags empty graph
__global__ void graph_count_kernel(const int* __restrict__ batch, float* __restrict__ rinvg, int n) {
    int g = threadIdx.x;
    if (g >= N_GRAPHS) return;
    int lo = 0, hi = n;
    while (lo < hi) { int mid = (lo + hi) >> 1; if (batch[mid] < g) lo = mid + 1; else hi = mid; }
    int lb0 = lo;
    int g1 = g + 1;
    lo = 0; hi = n;
    while (lo < hi) { int mid = (lo + hi) >> 1; if (batch[mid] < g1) lo = mid + 1; else hi = mid; }
    int cg = lo - lb0;
    rinvg[g] = (cg > 0) ? 1.0f / (float)cg : 0.0f;
}

// Gp partials: Ppart[b][g][f] = sum_{j in block b's range} c[j][g] * H1[j][f]
// LDS-staged outer products; thread owns 8 g x 4 f accumulators.
#define GP_NB 256
#define GP_T 16

__global__ __launch_bounds__(256) void gp_kernel(const float* __restrict__ c,
                                                 const float* __restrict__ H1,
                                                 float* __restrict__ Ppart, int n) {
    __shared__ float sc[GP_T][N_GRAPHS];
    __shared__ float sh[GP_T][D];
    int t = threadIdx.x;
    int b = blockIdx.x;
    int jpb = (n + GP_NB - 1) / GP_NB;
    int j0 = b * jpb;
    int j1 = min(j0 + jpb, n);
    int g0 = (t & 7) * 8;    // 8 graphs per thread
    int f0 = (t >> 3) * 4;   // 4 feats per thread
    float acc[8][4];
#pragma unroll
    for (int a = 0; a < 8; ++a)
#pragma unroll
        for (int q = 0; q < 4; ++q) acc[a][q] = 0.f;

    for (int jt = j0; jt < j1; jt += GP_T) {
        int cnt = min(GP_T, j1 - jt);
        // stage c tile: GP_T x 64 floats = 256 float4, 1/thread
        {
            int r = t >> 4, q = t & 15;
            float4 v = (r < cnt) ? *(const float4*)&c[(size_t)(jt + r) * N_GRAPHS + q * 4]
                                 : make_float4(0.f, 0.f, 0.f, 0.f);
            *(float4*)&sc[r][q * 4] = v;
        }
        // stage H1 tile: GP_T x 128 floats = 512 float4, 2/thread
#pragma unroll
        for (int j = 0; j < 2; ++j) {
            int idx = t + j * 256;
            int r = idx >> 5, q = idx & 31;
            float4 v = (r < cnt) ? *(const float4*)&H1[(size_t)(jt + r) * D + q * 4]
                                 : make_float4(0.f, 0.f, 0.f, 0.f);
            *(float4*)&sh[r][q * 4] = v;
        }
        __syncthreads();
#pragma unroll
        for (int r = 0; r < GP_T; ++r) {  // zero-padded rows contribute 0
            float cw[8], hv[4];
            *(float4*)&cw[0] = *(float4*)&sc[r][g0];
            *(float4*)&cw[4] = *(float4*)&sc[r][g0 + 4];
            *(float4*)&hv[0] = *(float4*)&sh[r][f0];
#pragma unroll
            for (int a = 0; a < 8; ++a)
#pragma unroll
                for (int q = 0; q < 4; ++q) acc[a][q] = fmaf(cw[a], hv[q], acc[a][q]);
        }
        __syncthreads();
    }
    float* P = &Ppart[(size_t)b * N_GRAPHS * D];
#pragma unroll
    for (int a = 0; a < 8; ++a)
        *(float4*)&P[(size_t)(g0 + a) * D + f0] =
            make_float4(acc[a][0], acc[a][1], acc[a][2], acc[a][3]);
}

// epilogue: out[g][f] = rinv_g * sum_k (sum_b Ppart[b][g][k]) * W2[k][f] + b2[f]
__global__ __launch_bounds__(128) void out_kernel(const float* __restrict__ Ppart,
                                                  const float* __restrict__ W2,
                                                  const float* __restrict__ b2,
                                                  const float* __restrict__ rinvg,
                                                  float* __restrict__ out) {
    __shared__ float gs[D];
    int g = blockIdx.x, f = threadIdx.x;
    float s = 0.f;
    for (int b = 0; b < GP_NB; ++b) s += Ppart[((size_t)b * N_GRAPHS + g) * D + f];
    gs[f] = s;
    __syncthreads();
    float acc = 0.f;
#pragma unroll 8
    for (int k = 0; k < D; ++k) acc = fmaf(gs[k], W2[k * D + f], acc);
    float r = rinvg[g];
    out[g * D + f] = (r > 0.f) ? fmaf(acc, r, b2[f]) : 0.f;  // empty graph -> 0 (matches ref)
}

// ---------------- launcher ----------------

extern "C" void kernel_launch(void* const* d_in, const int* in_sizes, int n_in,
                              void* d_out, int out_size, void* d_ws, size_t ws_size,
                              hipStream_t stream) {
    const float* x  = (const float*)d_in[0];
    const int*   ei = (const int*)d_in[1];
    const int*   batch = (const int*)d_in[2];
    const float* W1 = (const float*)d_in[3];
    const float* b1 = (const float*)d_in[4];
    const float* W2 = (const float*)d_in[5];
    const float* b2 = (const float*)d_in[6];
    float* out = (float*)d_out;

    const int n = in_sizes[2];       // 40000 nodes
    const int E = in_sizes[1] / 2;   // 640000 edges
    const int* src = ei;             // edge_index[0] = message sources
    const int* dst = ei + E;         // edge_index[1] = aggregation targets

    // workspace carve-up (256B aligned)
    char* ws = (char*)d_ws;
    size_t off = 0;
    auto carve = [&](size_t bytes) {
        size_t o = off;
        off = (off + bytes + 255) & ~(size_t)255;
        return (void*)(ws + o);
    };
    int*    cnt    = (int*)carve((size_t)n * 4);
    int*    rowptr = (int*)carve((size_t)(n + 1) * 4);
    float*  dinv   = (float*)carve((size_t)n * 4);
    unsigned long long* edges = (unsigned long long*)carve((size_t)E * 8);
    uint32* hb     = (uint32*)carve((size_t)n * D * 2);          // bf16 feature rows (10.24MB)
    float*  bufB   = (float*)carve((size_t)n * D * 4);           // H1 fp32 (20.48MB)
    float*  c      = (float*)carve((size_t)n * N_GRAPHS * 4);    // pooled coeffs (10.24MB)
    int*    tot    = (int*)carve(64 * 4);
    float*  rinvg  = (float*)carve(N_GRAPHS * 4);
    // aliases into hb (10.24MB): rank (2.56MB, dead after fill — gemm1 writes hb after);
    // Ppart (8MB, written by gp after agg1's last read of hb)
    int*    rank   = (int*)hb;
    float*  Ppart  = (float*)hb;
    (void)ws_size;

    const int nchunks = (n + 1023) >> 10;

    // zero-init (ws is poisoned 0xAA before every call)
    hipMemsetAsync(cnt, 0, (size_t)n * 4, stream);
    hipMemsetAsync(c, 0, (size_t)n * N_GRAPHS * 4, stream);

    // CSR build + pooled-coefficient matrix c (shared by both layers)
    count_rank_kernel<<<(E + 255) / 256, 256, 0, stream>>>(dst, cnt, rank, E);
    scanA_kernel<<<nchunks, 1024, 0, stream>>>(cnt, rowptr, tot, dinv, c, batch, n);
    scanB_kernel<<<nchunks, 1024, 0, stream>>>(rowptr, tot, n, nchunks);
    fill_kernel<<<(E + 255) / 256, 256, 0, stream>>>(src, dst, rowptr, rank, edges, dinv, c, batch, E);

    // layer 1: hb = bf16(x @ W1) ; agg + b1 + ReLU -> bufB (fp32 H1)
    gemm_kernel<<<(n + BM - 1) / BM, 256, 0, stream>>>(x, W1, hb, n);
    agg_kernel<<<(n + 7) / 8, 256, 0, stream>>>(hb, rowptr, edges, dinv, b1, bufB, n);

    // layer 2 + pool, algebraically fused: out = rinv * (c^T H1) W2 + b2
    graph_count_kernel<<<1, 64, 0, stream>>>(batch, rinvg, n);
    gp_kernel<<<GP_NB, 256, 0, stream>>>(c, bufB, Ppart, n);
    out_kernel<<<N_GRAPHS, 128, 0, stream>>>(Ppart, W2, b2, rinvg, out);
}

// Round 8
// 229.255 us; speedup vs baseline: 3.1641x; 1.0995x over previous
//
#include <hip/hip_runtime.h>

#define D 128
#define N_GRAPHS 64

typedef unsigned int uint32;
typedef __attribute__((ext_vector_type(8))) _Float16 f16x8;
typedef __attribute__((ext_vector_type(4))) float f32x4;

// fp16 helpers: dword holds 2 fp16 (low = elem 2i, high = elem 2i+1); RNE cvt
__device__ __forceinline__ float hl(uint32 u) {
    return (float)__builtin_bit_cast(_Float16, (unsigned short)(u & 0xFFFF));
}
__device__ __forceinline__ float hh(uint32 u) {
    return (float)__builtin_bit_cast(_Float16, (unsigned short)(u >> 16));
}
__device__ __forceinline__ uint32 h2pair(float a, float b) {
    unsigned short ua = __builtin_bit_cast(unsigned short, (_Float16)a);
    unsigned short ub = __builtin_bit_cast(unsigned short, (_Float16)b);
    return (uint32)ua | ((uint32)ub << 16);
}

// ---------------- CSR build ----------------

// count in-degree AND capture each edge's rank among its dst's edges
__global__ void count_rank_kernel(const int* __restrict__ dst, int* __restrict__ cnt,
                                  int* __restrict__ rank, int E) {
    int e = blockIdx.x * blockDim.x + threadIdx.x;
    if (e < E) rank[e] = atomicAdd(&cnt[dst[e]], 1);
}

// parallel scan, phase A. Fused: dinv; coalesced zeroing of this block's c rows
// + self-loop term c[i][batch[i]] = dinv_i^2 (ordered by the block barrier).
__global__ __launch_bounds__(1024) void scanA_kernel(const int* __restrict__ cnt,
                                                     int* __restrict__ rowptr,
                                                     int* __restrict__ tot,
                                                     float* __restrict__ dinv,
                                                     float* __restrict__ c,
                                                     const int* __restrict__ batch, int n) {
    __shared__ int swave[16];
    int t = threadIdx.x;
    int lane = t & 63, wave = t >> 6;
    int i = blockIdx.x * 1024 + t;
    // coalesced zero of c rows [blockIdx*1024, +1024) — replaces the 10.24MB memset
    {
        size_t f4base = (size_t)blockIdx.x * 1024 * 16;  // 16 float4 per 64-float row
        size_t f4lim = (size_t)n * 16;
        float4 z = make_float4(0.f, 0.f, 0.f, 0.f);
#pragma unroll
        for (int q = 0; q < 16; ++q) {
            size_t idx = f4base + (size_t)q * 1024 + t;
            if (idx < f4lim) ((float4*)c)[idx] = z;
        }
    }
    int orig = (i < n) ? cnt[i] : 0;
    int v = orig;
#pragma unroll
    for (int off = 1; off < 64; off <<= 1) {
        int u = __shfl_up(v, off, 64);
        if (lane >= off) v += u;
    }
    if (lane == 63) swave[wave] = v;
    __syncthreads();  // orders c-zeroing before the slot store below too
    if (wave == 0) {
        int wv = (lane < 16) ? swave[lane] : 0;
#pragma unroll
        for (int off = 1; off < 16; off <<= 1) {
            int u = __shfl_up(wv, off, 64);
            if (lane >= off) wv += u;
        }
        if (lane < 16) swave[lane] = wv;
    }
    if (i < n) {
        float dv = rsqrtf((float)(orig + 1));  // deg = in-deg + self loop
        dinv[i] = dv;
        c[(size_t)i * N_GRAPHS + batch[i]] = dv * dv;  // self-loop contribution
    }
    __syncthreads();
    int incl = v + ((wave > 0) ? swave[wave - 1] : 0);
    if (i < n) rowptr[i] = incl - orig;  // chunk-local exclusive
    if (t == 1023) tot[blockIdx.x] = incl;
}

// phase B: add chunk offsets (<=40 totals: serial per-block prefix is cheap)
__global__ __launch_bounds__(1024) void scanB_kernel(int* __restrict__ rowptr,
                                                     const int* __restrict__ tot,
                                                     int n, int nchunks) {
    __shared__ int soff;
    int b = blockIdx.x, t = threadIdx.x;
    if (t == 0) {
        int o = 0;
        for (int j = 0; j < b; ++j) o += tot[j];
        soff = o;
    }
    __syncthreads();
    int i = b * 1024 + t;
    if (i < n) rowptr[i] += soff;
    if (b == 0 && t == 0) {
        int o = 0;
        for (int j = 0; j < nchunks; ++j) o += tot[j];
        rowptr[n] = o;
    }
}

// scatter (col,wgt) packed as 8B (no atomics — rank precomputed), and
// accumulate the edge term of c: c[src][batch[dst]] += w
__global__ void fill_kernel(const int* __restrict__ src, const int* __restrict__ dst,
                            const int* __restrict__ rowptr, const int* __restrict__ rank,
                            unsigned long long* __restrict__ edges,
                            const float* __restrict__ dinv,
                            float* __restrict__ c, const int* __restrict__ batch, int E) {
    int e = blockIdx.x * blockDim.x + threadIdx.x;
    if (e < E) {
        int s = src[e], d = dst[e];
        int pos = rowptr[d] + rank[e];
        float w = dinv[s] * dinv[d];
        edges[pos] = (unsigned long long)(unsigned)s |
                     ((unsigned long long)__float_as_uint(w) << 32);
        atomicAdd(&c[(size_t)s * N_GRAPHS + batch[d]], w);
    }
}

// ---------------- MFMA fp16 GEMM: hb[M x 128](fp16) = fp16(A) @ fp16(W) ----------
// 64-row x 128-col block, 4 waves each 32x64. fp32->fp16 conversion fused into
// LDS staging. LDS rows padded to 136 fp16 (68 dw): frag reads are 2-way max.
// Fragment layouts (m89/m120-verified, dtype-independent): A[m=lane&15][k=quad*8+j],
// B[k=quad*8+j][n=lane&15] (W transposed in LDS), C/D col=lane&15, row=quad*4+reg.

#define GBM 64

__global__ __launch_bounds__(256) void mfma_gemm_kernel(const float* __restrict__ A,
                                                        const float* __restrict__ W,
                                                        uint32* __restrict__ hb, int M) {
    __shared__ uint32 lds[64 * 68 + 128 * 68];  // As 17408B + Wt 34816B = 52224B
    uint32* As = lds;             // [64 rows][68 dw]
    uint32* Wt = lds + 64 * 68;   // [128 n][68 dw] — W transposed
    int tid = threadIdx.x;
    int row0 = blockIdx.x * GBM;

    // stage A tile: 64x128 fp32 -> fp16 (2048 float4, 8/thread, coalesced)
#pragma unroll
    for (int j = 0; j < 8; ++j) {
        int idx = tid + j * 256;
        int r = idx >> 5, c4 = idx & 31;
        float4 v = make_float4(0.f, 0.f, 0.f, 0.f);
        if (row0 + r < M) v = *(const float4*)&A[(size_t)(row0 + r) * D + c4 * 4];
        As[r * 68 + c4 * 2 + 0] = h2pair(v.x, v.y);
        As[r * 68 + c4 * 2 + 1] = h2pair(v.z, v.w);
    }
    // stage W^T: thread owns column n, half the k range (lane-coalesced global reads)
    {
        int nn = tid & 127, half = tid >> 7;
        int kbase = half * 64;
#pragma unroll
        for (int kk = 0; kk < 64; kk += 2) {
            float v0 = W[(size_t)(kbase + kk) * D + nn];
            float v1 = W[(size_t)(kbase + kk + 1) * D + nn];
            Wt[nn * 68 + ((kbase + kk) >> 1)] = h2pair(v0, v1);
        }
    }
    __syncthreads();

    int wave = tid >> 6, lane = tid & 63;
    int quad = lane >> 4, l16 = lane & 15;
    int wr = (wave & 1) * 32;   // wave row base (2 m-tiles)
    int wc = (wave >> 1) * 64;  // wave col base (4 n-tiles)
    f32x4 acc[2][4];
#pragma unroll
    for (int mi = 0; mi < 2; ++mi)
#pragma unroll
        for (int ni = 0; ni < 4; ++ni) acc[mi][ni] = (f32x4){0.f, 0.f, 0.f, 0.f};

#pragma unroll
    for (int ks = 0; ks < 4; ++ks) {
        int kd = ks * 16 + quad * 4;  // dword offset of k0 + quad*8 fp16
        f16x8 a0 = *(f16x8*)&As[(wr + l16) * 68 + kd];
        f16x8 a1 = *(f16x8*)&As[(wr + 16 + l16) * 68 + kd];
        f16x8 b0 = *(f16x8*)&Wt[(wc + l16) * 68 + kd];
        f16x8 b1 = *(f16x8*)&Wt[(wc + 16 + l16) * 68 + kd];
        f16x8 b2 = *(f16x8*)&Wt[(wc + 32 + l16) * 68 + kd];
        f16x8 b3 = *(f16x8*)&Wt[(wc + 48 + l16) * 68 + kd];
        acc[0][0] = __builtin_amdgcn_mfma_f32_16x16x32_f16(a0, b0, acc[0][0], 0, 0, 0);
        acc[0][1] = __builtin_amdgcn_mfma_f32_16x16x32_f16(a0, b1, acc[0][1], 0, 0, 0);
        acc[0][2] = __builtin_amdgcn_mfma_f32_16x16x32_f16(a0, b2, acc[0][2], 0, 0, 0);
        acc[0][3] = __builtin_amdgcn_mfma_f32_16x16x32_f16(a0, b3, acc[0][3], 0, 0, 0);
        acc[1][0] = __builtin_amdgcn_mfma_f32_16x16x32_f16(a1, b0, acc[1][0], 0, 0, 0);
        acc[1][1] = __builtin_amdgcn_mfma_f32_16x16x32_f16(a1, b1, acc[1][1], 0, 0, 0);
        acc[1][2] = __builtin_amdgcn_mfma_f32_16x16x32_f16(a1, b2, acc[1][2], 0, 0, 0);
        acc[1][3] = __builtin_amdgcn_mfma_f32_16x16x32_f16(a1, b3, acc[1][3], 0, 0, 0);
    }
    __syncthreads();  // done reading As/Wt; reuse As region as C staging [64][128] fp16

    unsigned short* cs = (unsigned short*)lds;
#pragma unroll
    for (int mi = 0; mi < 2; ++mi)
#pragma unroll
        for (int ni = 0; ni < 4; ++ni)
#pragma unroll
            for (int r = 0; r < 4; ++r) {
                int row = wr + mi * 16 + quad * 4 + r;
                int col = wc + ni * 16 + l16;
                cs[row * 128 + col] =
                    __builtin_bit_cast(unsigned short, (_Float16)acc[mi][ni][r]);
            }
    __syncthreads();
    // coalesced write-out: 64 rows x 16 uint4; C-staging row = 128 fp16 = 64 DWORDS
    // (R6 bug: stride was r*32 — half of every row r>0 came from the wrong row)
#pragma unroll
    for (int j = 0; j < 4; ++j) {
        int idx = tid + j * 256;
        int r = idx >> 4, q = idx & 15;
        if (row0 + r < M)
            *(uint4*)&hb[(size_t)(row0 + r) * 64 + q * 4] = *(uint4*)&lds[r * 64 + q * 4];
    }
}

// ---------------- aggregation (gather over CSR) + bias + ReLU ----------------
// fp16 rows: 32-lane group per node, uint2 (8B = 4 fp16) per lane = 256B row/load.
// Block=128 (4 nodes): full occupancy with a shorter Poisson-degree tail.

__global__ __launch_bounds__(128) void agg_kernel(const uint32* __restrict__ hb,
                                                  const int* __restrict__ rowptr,
                                                  const unsigned long long* __restrict__ edges,
                                                  const float* __restrict__ dinv,
                                                  const float* __restrict__ bias,
                                                  float* __restrict__ out, int n) {
    int tid = threadIdx.x;
    int lane32 = tid & 31;   // features 4*lane32 .. 4*lane32+3
    int slot = tid >> 5;     // 0..3
    int node = blockIdx.x * 4 + slot;
    if (node >= n) return;
    const uint2* __restrict__ h2 = (const uint2*)hb;  // 32 uint2 per row

    float di = dinv[node];
    float ws = di * di;
    uint2 su = h2[(size_t)node * 32 + lane32];
    float a0 = ws * hl(su.x), a1 = ws * hh(su.x);
    float a2 = ws * hl(su.y), a3 = ws * hh(su.y);

    int k = rowptr[node], end = rowptr[node + 1];
    for (; k + 8 <= end; k += 8) {
        uint2 v[8];
        float w[8];
#pragma unroll
        for (int j = 0; j < 8; ++j) {
            unsigned long long u = edges[k + j];
            int s = (int)(unsigned)u;
            w[j] = __uint_as_float((unsigned)(u >> 32));
            v[j] = h2[(size_t)s * 32 + lane32];
        }
#pragma unroll
        for (int j = 0; j < 8; ++j) {
            a0 = fmaf(w[j], hl(v[j].x), a0);
            a1 = fmaf(w[j], hh(v[j].x), a1);
            a2 = fmaf(w[j], hl(v[j].y), a2);
            a3 = fmaf(w[j], hh(v[j].y), a3);
        }
    }
    for (; k < end; ++k) {
        unsigned long long u = edges[k];
        int s = (int)(unsigned)u;
        float w = __uint_as_float((unsigned)(u >> 32));
        uint2 v = h2[(size_t)s * 32 + lane32];
        a0 = fmaf(w, hl(v.x), a0);
        a1 = fmaf(w, hh(v.x), a1);
        a2 = fmaf(w, hl(v.y), a2);
        a3 = fmaf(w, hh(v.y), a3);
    }

    float4 b4 = ((const float4*)bias)[lane32];
    a0 = fmaxf(a0 + b4.x, 0.f);
    a1 = fmaxf(a1 + b4.y, 0.f);
    a2 = fmaxf(a2 + b4.z, 0.f);
    a3 = fmaxf(a3 + b4.w, 0.f);
    ((float4*)out)[(size_t)node * 32 + lane32] = make_float4(a0, a1, a2, a3);
}

// ---------------- pooled layer 2: out = rinv * (c^T H1) W2 + b2 ----------------

// Gp partials: Ppart[b][g][f] = sum_{j in block b's range} c[j][g] * H1[j][f]
#define GP_NB 256
#define GP_T 16

__global__ __launch_bounds__(256) void gp_kernel(const float* __restrict__ c,
                                                 const float* __restrict__ H1,
                                                 float* __restrict__ Ppart, int n) {
    __shared__ float sc[GP_T][N_GRAPHS];
    __shared__ float sh[GP_T][D];
    int t = threadIdx.x;
    int b = blockIdx.x;
    int jpb = (n + GP_NB - 1) / GP_NB;
    int j0 = b * jpb;
    int j1 = min(j0 + jpb, n);
    int g0 = (t & 7) * 8;    // 8 graphs per thread
    int f0 = (t >> 3) * 4;   // 4 feats per thread
    float acc[8][4];
#pragma unroll
    for (int a = 0; a < 8; ++a)
#pragma unroll
        for (int q = 0; q < 4; ++q) acc[a][q] = 0.f;

    for (int jt = j0; jt < j1; jt += GP_T) {
        int cnt = min(GP_T, j1 - jt);
        {
            int r = t >> 4, q = t & 15;
            float4 v = (r < cnt) ? *(const float4*)&c[(size_t)(jt + r) * N_GRAPHS + q * 4]
                                 : make_float4(0.f, 0.f, 0.f, 0.f);
            *(float4*)&sc[r][q * 4] = v;
        }
#pragma unroll
        for (int j = 0; j < 2; ++j) {
            int idx = t + j * 256;
            int r = idx >> 5, q = idx & 31;
            float4 v = (r < cnt) ? *(const float4*)&H1[(size_t)(jt + r) * D + q * 4]
                                 : make_float4(0.f, 0.f, 0.f, 0.f);
            *(float4*)&sh[r][q * 4] = v;
        }
        __syncthreads();
#pragma unroll
        for (int r = 0; r < GP_T; ++r) {
            float cw[8], hv[4];
            *(float4*)&cw[0] = *(float4*)&sc[r][g0];
            *(float4*)&cw[4] = *(float4*)&sc[r][g0 + 4];
            *(float4*)&hv[0] = *(float4*)&sh[r][f0];
#pragma unroll
            for (int a = 0; a < 8; ++a)
#pragma unroll
                for (int q = 0; q < 4; ++q) acc[a][q] = fmaf(cw[a], hv[q], acc[a][q]);
        }
        __syncthreads();
    }
    float* P = &Ppart[(size_t)b * N_GRAPHS * D];
#pragma unroll
    for (int a = 0; a < 8; ++a)
        *(float4*)&P[(size_t)(g0 + a) * D + f0] =
            make_float4(acc[a][0], acc[a][1], acc[a][2], acc[a][3]);
}

// epilogue: out[g][f] = rinv_g * sum_k (sum_b Ppart[b][g][k]) * W2[k][f] + b2[f]
// rinv computed in-block via binary search on sorted batch (graph_count folded in)
__global__ __launch_bounds__(128) void out_kernel(const float* __restrict__ Ppart,
                                                  const float* __restrict__ W2,
                                                  const float* __restrict__ b2,
                                                  const int* __restrict__ batch, int n,
                                                  float* __restrict__ out) {
    __shared__ float gs[D];
    __shared__ float srinv;
    int g = blockIdx.x, f = threadIdx.x;
    if (f == 0) {
        int lo = 0, hi = n;
        while (lo < hi) { int mid = (lo + hi) >> 1; if (batch[mid] < g) lo = mid + 1; else hi = mid; }
        int lb = lo;
        int g1 = g + 1;
        lo = 0; hi = n;
        while (lo < hi) { int mid = (lo + hi) >> 1; if (batch[mid] < g1) lo = mid + 1; else hi = mid; }
        int cg = lo - lb;
        srinv = (cg > 0) ? 1.0f / (float)cg : 0.0f;
    }
    float s = 0.f;
    for (int b = 0; b < GP_NB; ++b) s += Ppart[((size_t)b * N_GRAPHS + g) * D + f];
    gs[f] = s;
    __syncthreads();
    float acc = 0.f;
#pragma unroll 8
    for (int k = 0; k < D; ++k) acc = fmaf(gs[k], W2[k * D + f], acc);
    float r = srinv;
    out[g * D + f] = (r > 0.f) ? fmaf(acc, r, b2[f]) : 0.f;  // empty graph -> 0 (matches ref)
}

// ---------------- launcher ----------------

extern "C" void kernel_launch(void* const* d_in, const int* in_sizes, int n_in,
                              void* d_out, int out_size, void* d_ws, size_t ws_size,
                              hipStream_t stream) {
    const float* x  = (const float*)d_in[0];
    const int*   ei = (const int*)d_in[1];
    const int*   batch = (const int*)d_in[2];
    const float* W1 = (const float*)d_in[3];
    const float* b1 = (const float*)d_in[4];
    const float* W2 = (const float*)d_in[5];
    const float* b2 = (const float*)d_in[6];
    float* out = (float*)d_out;

    const int n = in_sizes[2];       // 40000 nodes
    const int E = in_sizes[1] / 2;   // 640000 edges
    const int* src = ei;             // edge_index[0] = message sources
    const int* dst = ei + E;         // edge_index[1] = aggregation targets

    // workspace carve-up (256B aligned)
    char* ws = (char*)d_ws;
    size_t off = 0;
    auto carve = [&](size_t bytes) {
        size_t o = off;
        off = (off + bytes + 255) & ~(size_t)255;
        return (void*)(ws + o);
    };
    int*    cnt    = (int*)carve((size_t)n * 4);
    int*    rowptr = (int*)carve((size_t)(n + 1) * 4);
    float*  dinv   = (float*)carve((size_t)n * 4);
    unsigned long long* edges = (unsigned long long*)carve((size_t)E * 8);
    uint32* hb     = (uint32*)carve((size_t)n * D * 2);          // fp16 feature rows (10.24MB)
    float*  bufB   = (float*)carve((size_t)n * D * 4);           // H1 fp32 (20.48MB)
    float*  c      = (float*)carve((size_t)n * N_GRAPHS * 4);    // pooled coeffs (10.24MB)
    int*    tot    = (int*)carve(64 * 4);
    // aliases into hb (10.24MB): rank (2.56MB, dead after fill — gemm1 writes hb after);
    // Ppart (8MB, written by gp after agg1's last read of hb)
    int*    rank   = (int*)hb;
    float*  Ppart  = (float*)hb;
    (void)ws_size;

    const int nchunks = (n + 1023) >> 10;

    // zero-init (ws is poisoned 0xAA before every call); c zeroing fused into scanA
    hipMemsetAsync(cnt, 0, (size_t)n * 4, stream);

    // CSR build + pooled-coefficient matrix c (shared by both layers)
    count_rank_kernel<<<(E + 255) / 256, 256, 0, stream>>>(dst, cnt, rank, E);
    scanA_kernel<<<nchunks, 1024, 0, stream>>>(cnt, rowptr, tot, dinv, c, batch, n);
    scanB_kernel<<<nchunks, 1024, 0, stream>>>(rowptr, tot, n, nchunks);
    fill_kernel<<<(E + 255) / 256, 256, 0, stream>>>(src, dst, rowptr, rank, edges, dinv, c, batch, E);

    // layer 1: hb = fp16(x @ W1) via MFMA ; agg + b1 + ReLU -> bufB (fp32 H1)
    mfma_gemm_kernel<<<(n + GBM - 1) / GBM, 256, 0, stream>>>(x, W1, hb, n);
    agg_kernel<<<(n + 3) / 4, 128, 0, stream>>>(hb, rowptr, edges, dinv, b1, bufB, n);

    // layer 2 + pool, algebraically fused: out = rinv * (c^T H1) W2 + b2
    gp_kernel<<<GP_NB, 256, 0, stream>>>(c, bufB, Ppart, n);
    out_kernel<<<N_GRAPHS, 128, 0, stream>>>(Ppart, W2, b2, batch, n, out);
}